// Round 2
// baseline (1011.534 us; speedup 1.0000x reference)
//
#include <hip/hip_runtime.h>
#include <math.h>

#define EPSF 1e-8f
#define PLANE ((size_t)256 * 4096)

__device__ __forceinline__ float sigf(float x) { return 1.0f / (1.0f + expf(-x)); }
__device__ __forceinline__ float softplusf(float x) { return x > 20.0f ? x : log1pf(expf(x)); }
__device__ __forceinline__ float dot4(float4 a, float4 b) {
  return a.x * b.x + a.y * b.y + a.z * b.z + a.w * b.w;
}

// ---------------- pack X = [in_data(64) | prev_reads(4x64) | h0(512)] : [256][832]
__global__ void pack_x_kernel(const float* __restrict__ in_data,
                              const float* __restrict__ prev_reads,
                              const float* __restrict__ h0,
                              float* __restrict__ X) {
  int idx = blockIdx.x * 256 + threadIdx.x;
  if (idx >= 256 * 832) return;
  int b = idx / 832, t = idx % 832;
  float v;
  if (t < 64) v = in_data[b * 64 + t];
  else if (t < 320) { int i = (t - 64) >> 6, m = (t - 64) & 63; v = prev_reads[((size_t)i * 256 + b) * 64 + m]; }
  else v = h0[b * 512 + (t - 320)];
  X[idx] = v;
}

// ---------------- gates = X @ [W_ih|W_hh]^T + b_ih + b_hh : [256][2048]
__global__ __launch_bounds__(256) void gemm_gates_kernel(
    const float* __restrict__ X, const float* __restrict__ W_ih,
    const float* __restrict__ W_hh, const float* __restrict__ b_ih,
    const float* __restrict__ b_hh, float* __restrict__ gates) {
  __shared__ float As[16][33];
  __shared__ float Ws[16][65];
  int tid = threadIdx.x, tx = tid & 15, ty = tid >> 4;
  int row0 = blockIdx.y * 32, col0 = blockIdx.x * 64;
  float acc[2][4] = {{0,0,0,0},{0,0,0,0}};
  for (int k0 = 0; k0 < 832; k0 += 16) {
    const float* Wp; int kw, KW;
    if (k0 < 320) { Wp = W_ih; kw = k0; KW = 320; }
    else          { Wp = W_hh; kw = k0 - 320; KW = 512; }
    for (int i = tid; i < 32 * 16; i += 256) {
      int rr = i >> 4, cc = i & 15;
      As[cc][rr] = X[(size_t)(row0 + rr) * 832 + k0 + cc];
    }
    for (int i = tid; i < 64 * 16; i += 256) {
      int rr = i >> 4, cc = i & 15;
      Ws[cc][rr] = Wp[(size_t)(col0 + rr) * KW + kw + cc];
    }
    __syncthreads();
#pragma unroll
    for (int kk = 0; kk < 16; kk++) {
      float a0 = As[kk][ty * 2 + 0], a1 = As[kk][ty * 2 + 1];
      float w0 = Ws[kk][tx * 4 + 0], w1 = Ws[kk][tx * 4 + 1];
      float w2 = Ws[kk][tx * 4 + 2], w3 = Ws[kk][tx * 4 + 3];
      acc[0][0] += a0 * w0; acc[0][1] += a0 * w1; acc[0][2] += a0 * w2; acc[0][3] += a0 * w3;
      acc[1][0] += a1 * w0; acc[1][1] += a1 * w1; acc[1][2] += a1 * w2; acc[1][3] += a1 * w3;
    }
    __syncthreads();
  }
  for (int i = 0; i < 2; i++)
    for (int j = 0; j < 4; j++) {
      int cc = col0 + tx * 4 + j;
      gates[(size_t)(row0 + ty * 2 + i) * 2048 + cc] = acc[i][j] + b_ih[cc] + b_hh[cc];
    }
}

// ---------------- LSTM elementwise: c,h
__global__ void lstm_elem_kernel(const float* __restrict__ gates,
                                 const float* __restrict__ c0,
                                 float* __restrict__ c, float* __restrict__ h) {
  int idx = blockIdx.x * 256 + threadIdx.x;
  if (idx >= 256 * 512) return;
  int b = idx >> 9, u = idx & 511;
  const float* g = gates + (size_t)b * 2048;
  float ig = sigf(g[u]), fg = sigf(g[512 + u]);
  float gg = tanhf(g[1024 + u]), og = sigf(g[1536 + u]);
  float cv = fg * c0[idx] + ig * gg;
  c[idx] = cv;
  h[idx] = og * tanhf(cv);
}

// ---------------- p_raw = c @ [W_addr(560)|W_ea(512)]^T + bias : [256][1072]
__global__ __launch_bounds__(256) void gemm_heads_kernel(
    const float* __restrict__ C, const float* __restrict__ W_addr,
    const float* __restrict__ W_ea, const float* __restrict__ b_addr,
    const float* __restrict__ b_ea, float* __restrict__ p_raw) {
  __shared__ float As[16][33];
  __shared__ float Ws[16][65];
  int tid = threadIdx.x, tx = tid & 15, ty = tid >> 4;
  int row0 = blockIdx.y * 32, col0 = blockIdx.x * 64;
  float acc[2][4] = {{0,0,0,0},{0,0,0,0}};
  for (int k0 = 0; k0 < 512; k0 += 16) {
    for (int i = tid; i < 32 * 16; i += 256) {
      int rr = i >> 4, cc = i & 15;
      As[cc][rr] = C[(size_t)(row0 + rr) * 512 + k0 + cc];
    }
    for (int i = tid; i < 64 * 16; i += 256) {
      int rr = i >> 4, cc = i & 15;
      int col = col0 + rr;
      float v = 0.f;
      if (col < 560) v = W_addr[(size_t)col * 512 + k0 + cc];
      else if (col < 1072) v = W_ea[(size_t)(col - 560) * 512 + k0 + cc];
      Ws[cc][rr] = v;
    }
    __syncthreads();
#pragma unroll
    for (int kk = 0; kk < 16; kk++) {
      float a0 = As[kk][ty * 2 + 0], a1 = As[kk][ty * 2 + 1];
      float w0 = Ws[kk][tx * 4 + 0], w1 = Ws[kk][tx * 4 + 1];
      float w2 = Ws[kk][tx * 4 + 2], w3 = Ws[kk][tx * 4 + 3];
      acc[0][0] += a0 * w0; acc[0][1] += a0 * w1; acc[0][2] += a0 * w2; acc[0][3] += a0 * w3;
      acc[1][0] += a1 * w0; acc[1][1] += a1 * w1; acc[1][2] += a1 * w2; acc[1][3] += a1 * w3;
    }
    __syncthreads();
  }
  for (int i = 0; i < 2; i++)
    for (int j = 0; j < 4; j++) {
      int col = col0 + tx * 4 + j;
      if (col < 1072) {
        float bias = col < 560 ? b_addr[col] : b_ea[col - 560];
        p_raw[(size_t)(row0 + ty * 2 + i) * 1072 + col] = acc[i][j] + bias;
      }
    }
}

// ---------------- unpack head params
__global__ void head_params_kernel(const float* __restrict__ p_raw,
    float* __restrict__ kvec, float* __restrict__ knorm,
    float* __restrict__ betav, float* __restrict__ gatev,
    float* __restrict__ sv, float* __restrict__ gammav,
    float* __restrict__ evec, float* __restrict__ avec) {
  int hi = blockIdx.x, b = blockIdx.y, t = threadIdx.x;
  const float* p = p_raw + (size_t)b * 1072 + hi * 70;
  if (t < 64) {
    float kvv = tanhf(p[t]);
    kvec[((size_t)hi * 256 + b) * 64 + t] = kvv;
    float s = kvv * kvv;
    for (int m = 1; m < 64; m <<= 1) s += __shfl_xor(s, m);
    if (t == 0) {
      int hb = hi * 256 + b;
      knorm[hb] = sqrtf(s);
      betav[hb] = softplusf(p[64]);
      gatev[hb] = sigf(p[65]);
      float a0 = p[66], a1 = p[67], a2 = p[68];
      float mm = fmaxf(a0, fmaxf(a1, a2));
      float e0 = expf(a0 - mm), e1 = expf(a1 - mm), e2 = expf(a2 - mm);
      float es = e0 + e1 + e2;
      sv[hb * 3 + 0] = e0 / es; sv[hb * 3 + 1] = e1 / es; sv[hb * 3 + 2] = e2 / es;
      gammav[hb] = 1.0f + softplusf(p[69]);
    }
  } else if ((hi & 1) && hi < 7) {      // write heads 1,3,5 -> slots 0,1,2 (head 7 dead)
    int wj = hi >> 1, t2 = t - 64;
    const float* ea = p_raw + (size_t)b * 1072 + 560 + wj * 128;
    evec[((size_t)wj * 256 + b) * 64 + t2] = sigf(ea[t2]);
    avec[((size_t)wj * 256 + b) * 64 + t2] = tanhf(ea[64 + t2]);
  }
}

// ---------------- build monomial vectors + per-b scalars for the write-expansion
// combo slots [20][B][64]:
//  0:k0 1:k1 2:k2 3:e1k2 4:k3 5:e1k3 6:a1 7:e1a1 8:e1 9:e1^2
//  10:k4 11:k5 12:k6 13:e5k6 14:a5 15:e5a5 16:e5 17:e5^2 18:e3 19:a3
// scal[b*8+]: 0:a1.k2 1:a1.k3 2:a1.a1 3:a5.k6 4:a5.a5
__global__ void combo_kernel(const float* __restrict__ kvec,
                             const float* __restrict__ evec,
                             const float* __restrict__ avec,
                             float* __restrict__ combo, float* __restrict__ scal) {
  int b = blockIdx.x, m = threadIdx.x;
  size_t bm = (size_t)b * 64 + m;
  float k0 = kvec[0 * 16384 + bm], k1 = kvec[1 * 16384 + bm];
  float k2 = kvec[2 * 16384 + bm], k3 = kvec[3 * 16384 + bm];
  float k4 = kvec[4 * 16384 + bm], k5 = kvec[5 * 16384 + bm];
  float k6 = kvec[6 * 16384 + bm];
  float e1 = evec[0 * 16384 + bm], a1 = avec[0 * 16384 + bm];
  float e3 = evec[1 * 16384 + bm], a3 = avec[1 * 16384 + bm];
  float e5 = evec[2 * 16384 + bm], a5 = avec[2 * 16384 + bm];
  combo[0 * 16384 + bm] = k0;  combo[1 * 16384 + bm] = k1;
  combo[2 * 16384 + bm] = k2;  combo[3 * 16384 + bm] = e1 * k2;
  combo[4 * 16384 + bm] = k3;  combo[5 * 16384 + bm] = e1 * k3;
  combo[6 * 16384 + bm] = a1;  combo[7 * 16384 + bm] = e1 * a1;
  combo[8 * 16384 + bm] = e1;  combo[9 * 16384 + bm] = e1 * e1;
  combo[10 * 16384 + bm] = k4; combo[11 * 16384 + bm] = k5;
  combo[12 * 16384 + bm] = k6; combo[13 * 16384 + bm] = e5 * k6;
  combo[14 * 16384 + bm] = a5; combo[15 * 16384 + bm] = e5 * a5;
  combo[16 * 16384 + bm] = e5; combo[17 * 16384 + bm] = e5 * e5;
  combo[18 * 16384 + bm] = e3; combo[19 * 16384 + bm] = a3;
  float s0 = a1 * k2, s1 = a1 * k3, s2 = a1 * a1, s3 = a5 * k6, s4 = a5 * a5;
#pragma unroll
  for (int d = 1; d < 64; d <<= 1) {
    s0 += __shfl_xor(s0, d); s1 += __shfl_xor(s1, d); s2 += __shfl_xor(s2, d);
    s3 += __shfl_xor(s3, d); s4 += __shfl_xor(s4, d);
  }
  if (m == 0) {
    scal[b * 8 + 0] = s0; scal[b * 8 + 1] = s1; scal[b * 8 + 2] = s2;
    scal[b * 8 + 3] = s3; scal[b * 8 + 4] = s4;
  }
}

#define LDC(j, q) (*(const float4*)(cb + (size_t)(j) * 16384 + (q) * 4))

// ---------------- pass 1 (transposed): 11 dots vs pristine mem0
// P1: 0..7 = m0.{k0,k1,k2,e1k2,k3,e1k3,a1,e1a1}; 8 = |m0|^2; 9 = m0^2.e1; 10 = m0^2.e1^2
__global__ __launch_bounds__(256) void dotpass1_kernel(
    const float* __restrict__ mem, const float* __restrict__ combo,
    float* __restrict__ P1) {
  extern __shared__ float4 tile[];
  const int NN = 4096;
  int b = blockIdx.y, n0 = blockIdx.x * 256, tid = threadIdx.x;
  const float4* m4 = (const float4*)mem + ((size_t)b * NN + n0) * 16;
#pragma unroll
  for (int i = 0; i < 16; i++) {
    int L = tid + i * 256, r = L >> 4, q = L & 15;
    tile[r * 16 + (q ^ (r & 15))] = m4[L];
  }
  __syncthreads();
  const float* cb = combo + (size_t)b * 64;
  float d0=0,d1=0,d2=0,d3=0,d4=0,d5=0,d6=0,d7=0,s0=0,s1=0,s2=0;
#pragma unroll
  for (int q = 0; q < 16; q++) {
    float4 v = tile[tid * 16 + (q ^ (tid & 15))];
    float4 sq = make_float4(v.x*v.x, v.y*v.y, v.z*v.z, v.w*v.w);
    d0 += dot4(v, LDC(0, q)); d1 += dot4(v, LDC(1, q));
    d2 += dot4(v, LDC(2, q)); d3 += dot4(v, LDC(3, q));
    d4 += dot4(v, LDC(4, q)); d5 += dot4(v, LDC(5, q));
    d6 += dot4(v, LDC(6, q)); d7 += dot4(v, LDC(7, q));
    s0 += sq.x + sq.y + sq.z + sq.w;
    s1 += dot4(sq, LDC(8, q)); s2 += dot4(sq, LDC(9, q));
  }
  size_t o = (size_t)b * NN + n0 + tid;
  P1[0*PLANE+o]=d0; P1[1*PLANE+o]=d1; P1[2*PLANE+o]=d2; P1[3*PLANE+o]=d3;
  P1[4*PLANE+o]=d4; P1[5*PLANE+o]=d5; P1[6*PLANE+o]=d6; P1[7*PLANE+o]=d7;
  P1[8*PLANE+o]=s0; P1[9*PLANE+o]=s1; P1[10*PLANE+o]=s2;
}

// ---------------- pass 2: build mem2 in regs (u1,u3), 9 dots vs mem2; then read0/read2
// P2: 0..5 = m2.{k4,k5,k6,e5k6,a5,e5a5}; 6 = |m2|^2; 7 = m2^2.e5; 8 = m2^2.e5^2
__global__ __launch_bounds__(256) void dotpass2_kernel(
    const float* __restrict__ mem, const float* __restrict__ combo,
    const float* __restrict__ w_all, float* __restrict__ P2,
    float* __restrict__ reads) {
  extern __shared__ float4 tile[];
  const int NN = 4096;
  int b = blockIdx.y, n0 = blockIdx.x * 256, tid = threadIdx.x;
  size_t bo = (size_t)b * NN;
  const float4* m4 = (const float4*)mem + (bo + n0) * 16;
#pragma unroll
  for (int i = 0; i < 16; i++) {
    int L = tid + i * 256, r = L >> 4, q = L & 15;
    tile[r * 16 + (q ^ (r & 15))] = m4[L];
  }
  __syncthreads();
  const float* cb = combo + (size_t)b * 64;
  float u1 = w_all[1 * PLANE + bo + n0 + tid];
  float u3 = w_all[3 * PLANE + bo + n0 + tid];
  float t0=0,t1=0,t2=0,t3=0,t4=0,t5=0,r0=0,r1=0,r2=0;
#pragma unroll
  for (int q = 0; q < 16; q++) {
    float4 v = tile[tid * 16 + (q ^ (tid & 15))];
    float4 e1 = LDC(8, q), aa1 = LDC(6, q), e3 = LDC(18, q), aa3 = LDC(19, q);
    float4 m1, m2;
    m1.x = v.x * (1.f - u1 * e1.x) + u1 * aa1.x;
    m1.y = v.y * (1.f - u1 * e1.y) + u1 * aa1.y;
    m1.z = v.z * (1.f - u1 * e1.z) + u1 * aa1.z;
    m1.w = v.w * (1.f - u1 * e1.w) + u1 * aa1.w;
    m2.x = m1.x * (1.f - u3 * e3.x) + u3 * aa3.x;
    m2.y = m1.y * (1.f - u3 * e3.y) + u3 * aa3.y;
    m2.z = m1.z * (1.f - u3 * e3.z) + u3 * aa3.z;
    m2.w = m1.w * (1.f - u3 * e3.w) + u3 * aa3.w;
    float4 sq = make_float4(m2.x*m2.x, m2.y*m2.y, m2.z*m2.z, m2.w*m2.w);
    t0 += dot4(m2, LDC(10, q)); t1 += dot4(m2, LDC(11, q));
    t2 += dot4(m2, LDC(12, q)); t3 += dot4(m2, LDC(13, q));
    t4 += dot4(m2, LDC(14, q)); t5 += dot4(m2, LDC(15, q));
    r0 += sq.x + sq.y + sq.z + sq.w;
    r1 += dot4(sq, LDC(16, q)); r2 += dot4(sq, LDC(17, q));
  }
  size_t o = bo + n0 + tid;
  P2[0*PLANE+o]=t0; P2[1*PLANE+o]=t1; P2[2*PLANE+o]=t2; P2[3*PLANE+o]=t3;
  P2[4*PLANE+o]=t4; P2[5*PLANE+o]=t5; P2[6*PLANE+o]=r0; P2[7*PLANE+o]=r1; P2[8*PLANE+o]=r2;

  // phase B (original layout from LDS): read0 (mem0,w0), read2 (mem1,w2)
  __shared__ float sredA[4][16][4];
  __shared__ float sredB[4][16][4];
  int wv = tid >> 6, lane = tid & 63, q = lane & 15, rl = lane >> 4;
  float4 e1q = LDC(8, q), a1q = LDC(6, q);
  const float* w0r = w_all + 0 * PLANE + bo;
  const float* w1r = w_all + 1 * PLANE + bo;
  const float* w2r = w_all + 2 * PLANE + bo;
  float ax=0, ay=0, az=0, aw=0, bx=0, by=0, bz=0, bw=0;
#pragma unroll 4
  for (int t = 0; t < 16; t++) {
    int nl = wv * 64 + t * 4 + rl, n = n0 + nl;
    float4 v = tile[nl * 16 + (q ^ (nl & 15))];
    float w0v = w0r[n], u1b = w1r[n], w2v = w2r[n];
    ax += w0v * v.x; ay += w0v * v.y; az += w0v * v.z; aw += w0v * v.w;
    float m1x = v.x * (1.f - u1b * e1q.x) + u1b * a1q.x;
    float m1y = v.y * (1.f - u1b * e1q.y) + u1b * a1q.y;
    float m1z = v.z * (1.f - u1b * e1q.z) + u1b * a1q.z;
    float m1w = v.w * (1.f - u1b * e1q.w) + u1b * a1q.w;
    bx += w2v * m1x; by += w2v * m1y; bz += w2v * m1z; bw += w2v * m1w;
  }
#pragma unroll
  for (int m = 16; m < 64; m <<= 1) {
    ax += __shfl_xor(ax, m); ay += __shfl_xor(ay, m); az += __shfl_xor(az, m); aw += __shfl_xor(aw, m);
    bx += __shfl_xor(bx, m); by += __shfl_xor(by, m); bz += __shfl_xor(bz, m); bw += __shfl_xor(bw, m);
  }
  if (rl == 0) {
    sredA[wv][q][0]=ax; sredA[wv][q][1]=ay; sredA[wv][q][2]=az; sredA[wv][q][3]=aw;
    sredB[wv][q][0]=bx; sredB[wv][q][1]=by; sredB[wv][q][2]=bz; sredB[wv][q][3]=bw;
  }
  __syncthreads();
  if (tid < 64) {
    int qq = tid >> 2, cc = tid & 3;
    float sA = sredA[0][qq][cc] + sredA[1][qq][cc] + sredA[2][qq][cc] + sredA[3][qq][cc];
    float sB = sredB[0][qq][cc] + sredB[1][qq][cc] + sredB[2][qq][cc] + sredB[3][qq][cc];
    atomicAdd(&reads[0 * 16384 + b * 64 + qq * 4 + cc], sA);
    atomicAdd(&reads[1 * 16384 + b * 64 + qq * 4 + cc], sB);
  }
}

// ---------------- pass 3: read4 (mem2, w4) + read6 (mem3, w6), streaming mem0
__global__ __launch_bounds__(256) void readpass_kernel(
    const float* __restrict__ mem, const float* __restrict__ w_all,
    const float* __restrict__ evec, const float* __restrict__ avec,
    float* __restrict__ reads) {
  const int NN = 4096;
  int b = blockIdx.y, n0 = blockIdx.x * 256, tid = threadIdx.x;
  int wv = tid >> 6, lane = tid & 63, q = lane & 15, rl = lane >> 4;
  size_t bo = (size_t)b * NN;
  float4 e1 = *(const float4*)(evec + 0 * 16384 + b * 64 + q * 4);
  float4 a1 = *(const float4*)(avec + 0 * 16384 + b * 64 + q * 4);
  float4 e3 = *(const float4*)(evec + 1 * 16384 + b * 64 + q * 4);
  float4 a3 = *(const float4*)(avec + 1 * 16384 + b * 64 + q * 4);
  float4 e5 = *(const float4*)(evec + 2 * 16384 + b * 64 + q * 4);
  float4 a5 = *(const float4*)(avec + 2 * 16384 + b * 64 + q * 4);
  const float* w1r = w_all + 1 * PLANE + bo;
  const float* w3r = w_all + 3 * PLANE + bo;
  const float* w5r = w_all + 5 * PLANE + bo;
  const float* w4r = w_all + 4 * PLANE + bo;
  const float* w6r = w_all + 6 * PLANE + bo;
  __shared__ float sredA[4][16][4];
  __shared__ float sredB[4][16][4];
  const float4* m4 = (const float4*)mem;
  size_t base = (bo + n0 + (size_t)wv * 64) * 16 + lane;
  float ax=0, ay=0, az=0, aw=0, bx=0, by=0, bz=0, bw=0;
#pragma unroll 4
  for (int t = 0; t < 16; t++) {
    int nl = wv * 64 + t * 4 + rl, n = n0 + nl;
    float4 v = m4[base + (size_t)t * 64];
    float u1 = w1r[n], u3 = w3r[n], u5 = w5r[n], w4v = w4r[n], w6v = w6r[n];
    float m1x = v.x * (1.f - u1 * e1.x) + u1 * a1.x;
    float m1y = v.y * (1.f - u1 * e1.y) + u1 * a1.y;
    float m1z = v.z * (1.f - u1 * e1.z) + u1 * a1.z;
    float m1w = v.w * (1.f - u1 * e1.w) + u1 * a1.w;
    float m2x = m1x * (1.f - u3 * e3.x) + u3 * a3.x;
    float m2y = m1y * (1.f - u3 * e3.y) + u3 * a3.y;
    float m2z = m1z * (1.f - u3 * e3.z) + u3 * a3.z;
    float m2w = m1w * (1.f - u3 * e3.w) + u3 * a3.w;
    ax += w4v * m2x; ay += w4v * m2y; az += w4v * m2z; aw += w4v * m2w;
    float m3x = m2x * (1.f - u5 * e5.x) + u5 * a5.x;
    float m3y = m2y * (1.f - u5 * e5.y) + u5 * a5.y;
    float m3z = m2z * (1.f - u5 * e5.z) + u5 * a5.z;
    float m3w = m2w * (1.f - u5 * e5.w) + u5 * a5.w;
    bx += w6v * m3x; by += w6v * m3y; bz += w6v * m3z; bw += w6v * m3w;
  }
#pragma unroll
  for (int m = 16; m < 64; m <<= 1) {
    ax += __shfl_xor(ax, m); ay += __shfl_xor(ay, m); az += __shfl_xor(az, m); aw += __shfl_xor(aw, m);
    bx += __shfl_xor(bx, m); by += __shfl_xor(by, m); bz += __shfl_xor(bz, m); bw += __shfl_xor(bw, m);
  }
  if (rl == 0) {
    sredA[wv][q][0]=ax; sredA[wv][q][1]=ay; sredA[wv][q][2]=az; sredA[wv][q][3]=aw;
    sredB[wv][q][0]=bx; sredB[wv][q][1]=by; sredB[wv][q][2]=bz; sredB[wv][q][3]=bw;
  }
  __syncthreads();
  if (tid < 64) {
    int qq = tid >> 2, cc = tid & 3;
    float sA = sredA[0][qq][cc] + sredA[1][qq][cc] + sredA[2][qq][cc] + sredA[3][qq][cc];
    float sB = sredB[0][qq][cc] + sredB[1][qq][cc] + sredB[2][qq][cc] + sredB[3][qq][cc];
    atomicAdd(&reads[2 * 16384 + b * 64 + qq * 4 + cc], sA);
    atomicAdd(&reads[3 * 16384 + b * 64 + qq * 4 + cc], sB);
  }
}

// ---------------- addressing chain: score(direct or expanded)->softmax->interp->shift->sharpen->w
template<int MODE>  // 0: direct (score from Da, S0); 1: expanded via write algebra
__global__ __launch_bounds__(256) void chain_kernel(
    const float* __restrict__ DaA, const float* __restrict__ DaB,
    const float* __restrict__ DbA, const float* __restrict__ DbB,
    const float* __restrict__ D6, const float* __restrict__ D7,
    const float* __restrict__ S0, const float* __restrict__ S1,
    const float* __restrict__ S2, const float* __restrict__ uplane,
    const float* __restrict__ scal, int cak_slot, int caa_slot,
    const float* __restrict__ knorm, const float* __restrict__ betav,
    const float* __restrict__ gatev, const float* __restrict__ sv,
    const float* __restrict__ gammav, const float* __restrict__ prev_w,
    float* __restrict__ w_all, int head_base) {
  const int NN = 4096, BB = 256;
  int which = blockIdx.x, b = blockIdx.y;
  int head = head_base + which;
  const float* Da = which ? DaB : DaA;
  const float* Db = which ? DbB : DbA;
  size_t bo = (size_t)b * NN;
  __shared__ float wg[4096];
  __shared__ float redm[4], reds[4], reds2[4];
  int tid = threadIdx.x;
  int lane = tid & 63, wv = tid >> 6;
  int hb = head * BB + b;
  float kn = knorm[hb], be = betav[hb], ga = gatev[hb], gm = gammav[hb];
  float s0 = sv[hb * 3 + 0], s1 = sv[hb * 3 + 1], s2 = sv[hb * 3 + 2];
  float cak = 0.f, caa = 0.f;
  if (MODE) { cak = scal[b * 8 + cak_slot + which]; caa = scal[b * 8 + caa_slot]; }

  float sc[16];
  float mx = -1e30f;
#pragma unroll
  for (int i = 0; i < 16; i++) {
    int n = tid + i * 256;
    float d, nn2;
    if (MODE) {
      float u = uplane[bo + n];
      d = Da[bo + n] - u * Db[bo + n] + u * cak;
      nn2 = S0[bo + n] - 2.f * u * S1[bo + n] + u * u * S2[bo + n]
          + 2.f * u * D6[bo + n] - 2.f * u * u * D7[bo + n] + u * u * caa;
      nn2 = fmaxf(nn2, 0.f);
    } else {
      d = Da[bo + n];
      nn2 = S0[bo + n];
    }
    sc[i] = be * d / (sqrtf(nn2) * kn + EPSF);
    mx = fmaxf(mx, sc[i]);
  }
  for (int m = 1; m < 64; m <<= 1) mx = fmaxf(mx, __shfl_xor(mx, m));
  if (lane == 0) redm[wv] = mx;
  __syncthreads();
  mx = fmaxf(fmaxf(redm[0], redm[1]), fmaxf(redm[2], redm[3]));
  float sum = 0.f;
#pragma unroll
  for (int i = 0; i < 16; i++) { sc[i] = expf(sc[i] - mx); sum += sc[i]; }
  for (int m = 1; m < 64; m <<= 1) sum += __shfl_xor(sum, m);
  if (lane == 0) reds[wv] = sum;
  __syncthreads();
  sum = reds[0] + reds[1] + reds[2] + reds[3];
  float inv = 1.0f / sum;
  const float* pw = prev_w + (size_t)head * BB * NN + bo;
#pragma unroll
  for (int i = 0; i < 16; i++) {
    int n = tid + i * 256;
    wg[n] = ga * (sc[i] * inv) + (1.f - ga) * pw[n];
  }
  __syncthreads();
  float wp[16];
  float sum2 = 0.f;
#pragma unroll
  for (int i = 0; i < 16; i++) {
    int n = tid + i * 256;
    float wsv = s0 * wg[(n + NN - 1) & (NN - 1)] + s1 * wg[n] + s2 * wg[(n + 1) & (NN - 1)];
    wp[i] = powf(wsv, gm);
    sum2 += wp[i];
  }
  for (int m = 1; m < 64; m <<= 1) sum2 += __shfl_xor(sum2, m);
  if (lane == 0) reds2[wv] = sum2;
  __syncthreads();
  sum2 = reds2[0] + reds2[1] + reds2[2] + reds2[3];
  float invs = 1.0f / (sum2 + EPSF);
  float* wo = w_all + (size_t)head * BB * NN + bo;
#pragma unroll
  for (int i = 0; i < 16; i++) wo[tid + i * 256] = wp[i] * invs;
}

// ---------------- state = [h | read0 | read2 | read4 | read6] : [256][768]
__global__ void pack_state_kernel(const float* __restrict__ h,
                                  const float* __restrict__ reads,
                                  float* __restrict__ state) {
  int idx = blockIdx.x * 256 + threadIdx.x;
  if (idx >= 256 * 768) return;
  int b = idx / 768, t = idx % 768;
  float v;
  if (t < 512) v = h[b * 512 + t];
  else { int slot = (t - 512) >> 6, m = (t - 512) & 63; v = reads[((size_t)slot * 256 + b) * 64 + m]; }
  state[idx] = v;
}

// ---------------- out = sigmoid(state @ W_out^T + b_out) : [256][64]
__global__ __launch_bounds__(256) void gemm_out_kernel(
    const float* __restrict__ state, const float* __restrict__ W_out,
    const float* __restrict__ b_out, float* __restrict__ out) {
  __shared__ float As[16][33];
  __shared__ float Ws[16][65];
  int tid = threadIdx.x, tx = tid & 15, ty = tid >> 4;
  int row0 = blockIdx.y * 32;
  float acc[2][4] = {{0,0,0,0},{0,0,0,0}};
  for (int k0 = 0; k0 < 768; k0 += 16) {
    for (int i = tid; i < 32 * 16; i += 256) {
      int rr = i >> 4, cc = i & 15;
      As[cc][rr] = state[(size_t)(row0 + rr) * 768 + k0 + cc];
    }
    for (int i = tid; i < 64 * 16; i += 256) {
      int rr = i >> 4, cc = i & 15;
      Ws[cc][rr] = W_out[(size_t)rr * 768 + k0 + cc];
    }
    __syncthreads();
#pragma unroll
    for (int kk = 0; kk < 16; kk++) {
      float a0 = As[kk][ty * 2 + 0], a1 = As[kk][ty * 2 + 1];
      float w0 = Ws[kk][tx * 4 + 0], w1 = Ws[kk][tx * 4 + 1];
      float w2 = Ws[kk][tx * 4 + 2], w3 = Ws[kk][tx * 4 + 3];
      acc[0][0] += a0 * w0; acc[0][1] += a0 * w1; acc[0][2] += a0 * w2; acc[0][3] += a0 * w3;
      acc[1][0] += a1 * w0; acc[1][1] += a1 * w1; acc[1][2] += a1 * w2; acc[1][3] += a1 * w3;
    }
    __syncthreads();
  }
  for (int i = 0; i < 2; i++)
    for (int j = 0; j < 4; j++) {
      int cc = tx * 4 + j;
      out[(size_t)(row0 + ty * 2 + i) * 64 + cc] = sigf(acc[i][j] + b_out[cc]);
    }
}

extern "C" void kernel_launch(void* const* d_in, const int* in_sizes, int n_in,
                              void* d_out, int out_size, void* d_ws, size_t ws_size,
                              hipStream_t stream) {
  const float* in_data = (const float*)d_in[0];
  const float* memory  = (const float*)d_in[1];
  const float* h0      = (const float*)d_in[2];
  const float* c0      = (const float*)d_in[3];
  const float* prev_w  = (const float*)d_in[4];
  const float* prev_r  = (const float*)d_in[5];
  const float* W_ih    = (const float*)d_in[6];
  const float* b_ih    = (const float*)d_in[7];
  const float* W_hh    = (const float*)d_in[8];
  const float* b_hh    = (const float*)d_in[9];
  const float* W_out   = (const float*)d_in[10];
  const float* b_out   = (const float*)d_in[11];
  const float* W_addr  = (const float*)d_in[12];
  const float* b_addr  = (const float*)d_in[13];
  const float* W_ea    = (const float*)d_in[14];
  const float* b_ea    = (const float*)d_in[15];
  float* out = (float*)d_out;
  (void)in_sizes; (void)n_in; (void)out_size; (void)ws_size;

  float* ws = (float*)d_ws;
  size_t off = 0;
  auto alloc = [&](size_t n) { float* p = ws + off; off += (n + 63) & ~(size_t)63; return p; };
  float* X      = alloc(256 * 832);
  float* gates  = alloc(256 * 2048);
  float* cbuf   = alloc(256 * 512);
  float* hbuf   = alloc(256 * 512);
  float* p_raw  = alloc(256 * 1072);
  float* kvec   = alloc(8 * 256 * 64);
  float* knorm  = alloc(8 * 256);
  float* betav  = alloc(8 * 256);
  float* gatev  = alloc(8 * 256);
  float* sv     = alloc(8 * 256 * 3);
  float* gammav = alloc(8 * 256);
  float* evec   = alloc(3 * 256 * 64);
  float* avec   = alloc(3 * 256 * 64);
  float* combo  = alloc(20 * 256 * 64);
  float* scal   = alloc(256 * 8);
  float* P1     = alloc(11 * PLANE);
  float* P2     = alloc(9 * PLANE);
  float* w_all  = alloc(7 * PLANE);
  float* reads  = alloc(4 * 256 * 64);
  float* state  = alloc(256 * 768);

  hipMemsetAsync(reads, 0, 4 * 256 * 64 * sizeof(float), stream);

  pack_x_kernel<<<(256 * 832 + 255) / 256, 256, 0, stream>>>(in_data, prev_r, h0, X);
  gemm_gates_kernel<<<dim3(32, 8), 256, 0, stream>>>(X, W_ih, W_hh, b_ih, b_hh, gates);
  lstm_elem_kernel<<<(256 * 512 + 255) / 256, 256, 0, stream>>>(gates, c0, cbuf, hbuf);
  gemm_heads_kernel<<<dim3(17, 8), 256, 0, stream>>>(cbuf, W_addr, W_ea, b_addr, b_ea, p_raw);
  head_params_kernel<<<dim3(8, 256), 128, 0, stream>>>(p_raw, kvec, knorm, betav, gatev, sv, gammav, evec, avec);
  combo_kernel<<<256, 64, 0, stream>>>(kvec, evec, avec, combo, scal);

  dim3 pgrid(16, 256);
  dotpass1_kernel<<<pgrid, 256, 65536, stream>>>(memory, combo, P1);
  // heads 0,1: direct scores vs mem0
  chain_kernel<0><<<dim3(2, 256), 256, 0, stream>>>(
      P1 + 0 * PLANE, P1 + 1 * PLANE, nullptr, nullptr, nullptr, nullptr,
      P1 + 8 * PLANE, nullptr, nullptr, nullptr, scal, 0, 0,
      knorm, betav, gatev, sv, gammav, prev_w, w_all, 0);
  // heads 2,3: expanded via u1 = w_all[1]
  chain_kernel<1><<<dim3(2, 256), 256, 0, stream>>>(
      P1 + 2 * PLANE, P1 + 4 * PLANE, P1 + 3 * PLANE, P1 + 5 * PLANE,
      P1 + 6 * PLANE, P1 + 7 * PLANE,
      P1 + 8 * PLANE, P1 + 9 * PLANE, P1 + 10 * PLANE, w_all + 1 * PLANE,
      scal, 0, 2,
      knorm, betav, gatev, sv, gammav, prev_w, w_all, 2);
  dotpass2_kernel<<<pgrid, 256, 65536, stream>>>(memory, combo, w_all, P2, reads);
  // heads 4,5: direct scores vs mem2
  chain_kernel<0><<<dim3(2, 256), 256, 0, stream>>>(
      P2 + 0 * PLANE, P2 + 1 * PLANE, nullptr, nullptr, nullptr, nullptr,
      P2 + 6 * PLANE, nullptr, nullptr, nullptr, scal, 0, 0,
      knorm, betav, gatev, sv, gammav, prev_w, w_all, 4);
  // head 6: expanded via u5 = w_all[5]
  chain_kernel<1><<<dim3(1, 256), 256, 0, stream>>>(
      P2 + 2 * PLANE, nullptr, P2 + 3 * PLANE, nullptr,
      P2 + 4 * PLANE, P2 + 5 * PLANE,
      P2 + 6 * PLANE, P2 + 7 * PLANE, P2 + 8 * PLANE, w_all + 5 * PLANE,
      scal, 3, 4,
      knorm, betav, gatev, sv, gammav, prev_w, w_all, 6);
  readpass_kernel<<<pgrid, 256, 0, stream>>>(memory, w_all, evec, avec, reads);

  pack_state_kernel<<<(256 * 768 + 255) / 256, 256, 0, stream>>>(hbuf, reads, state);
  gemm_out_kernel<<<dim3(1, 8), 256, 0, stream>>>(state, W_out, b_out, out);
}

// Round 3
// 921.911 us; speedup vs baseline: 1.0972x; 1.0972x over previous
//
#include <hip/hip_runtime.h>
#include <math.h>

#define EPSF 1e-8f
#define PLANE ((size_t)256 * 4096)

__device__ __forceinline__ float sigf(float x) { return 1.0f / (1.0f + expf(-x)); }
__device__ __forceinline__ float softplusf(float x) { return x > 20.0f ? x : log1pf(expf(x)); }
__device__ __forceinline__ float dot4(float4 a, float4 b) {
  return a.x * b.x + a.y * b.y + a.z * b.z + a.w * b.w;
}
__device__ __forceinline__ unsigned short f2bf(float x) {
  unsigned int u = __float_as_uint(x);
  unsigned int r = (u + 0x7FFF + ((u >> 16) & 1)) >> 16;
  return (unsigned short)r;
}
__device__ __forceinline__ float bf2f(unsigned int lo16) {
  return __uint_as_float(lo16 << 16);
}

// ---------------- X gather: [in_data(64) | prev_reads(4x64) | h0(512)]
__device__ __forceinline__ float gather_x(const float* __restrict__ in_data,
                                          const float* __restrict__ prev_reads,
                                          const float* __restrict__ h0,
                                          int row, int k) {
  if (k < 64) return in_data[row * 64 + k];
  if (k < 320) { int i = (k - 64) >> 6, m = (k - 64) & 63; return prev_reads[((size_t)i * 256 + row) * 64 + m]; }
  return h0[row * 512 + (k - 320)];
}

// ---------------- gates = [X|h0] @ [W_ih|W_hh]^T + b_ih + b_hh : [256][2048]
__global__ __launch_bounds__(256) void gemm_gates_kernel(
    const float* __restrict__ in_data, const float* __restrict__ prev_reads,
    const float* __restrict__ h0, const float* __restrict__ W_ih,
    const float* __restrict__ W_hh, const float* __restrict__ b_ih,
    const float* __restrict__ b_hh, float* __restrict__ gates) {
  __shared__ float As[16][33];
  __shared__ float Ws[16][65];
  int tid = threadIdx.x, tx = tid & 15, ty = tid >> 4;
  int row0 = blockIdx.y * 32, col0 = blockIdx.x * 64;
  float acc[2][4] = {{0,0,0,0},{0,0,0,0}};
  for (int k0 = 0; k0 < 832; k0 += 16) {
    const float* Wp; int kw, KW;
    if (k0 < 320) { Wp = W_ih; kw = k0; KW = 320; }
    else          { Wp = W_hh; kw = k0 - 320; KW = 512; }
    for (int i = tid; i < 32 * 16; i += 256) {
      int rr = i >> 4, cc = i & 15;
      As[cc][rr] = gather_x(in_data, prev_reads, h0, row0 + rr, k0 + cc);
    }
    for (int i = tid; i < 64 * 16; i += 256) {
      int rr = i >> 4, cc = i & 15;
      Ws[cc][rr] = Wp[(size_t)(col0 + rr) * KW + kw + cc];
    }
    __syncthreads();
#pragma unroll
    for (int kk = 0; kk < 16; kk++) {
      float a0 = As[kk][ty * 2 + 0], a1 = As[kk][ty * 2 + 1];
      float w0 = Ws[kk][tx * 4 + 0], w1 = Ws[kk][tx * 4 + 1];
      float w2 = Ws[kk][tx * 4 + 2], w3 = Ws[kk][tx * 4 + 3];
      acc[0][0] += a0 * w0; acc[0][1] += a0 * w1; acc[0][2] += a0 * w2; acc[0][3] += a0 * w3;
      acc[1][0] += a1 * w0; acc[1][1] += a1 * w1; acc[1][2] += a1 * w2; acc[1][3] += a1 * w3;
    }
    __syncthreads();
  }
  for (int i = 0; i < 2; i++)
    for (int j = 0; j < 4; j++) {
      int cc = col0 + tx * 4 + j;
      gates[(size_t)(row0 + ty * 2 + i) * 2048 + cc] = acc[i][j] + b_ih[cc] + b_hh[cc];
    }
}

// ---------------- LSTM elementwise: c,h
__global__ void lstm_elem_kernel(const float* __restrict__ gates,
                                 const float* __restrict__ c0,
                                 float* __restrict__ c, float* __restrict__ h) {
  int idx = blockIdx.x * 256 + threadIdx.x;
  if (idx >= 256 * 512) return;
  int b = idx >> 9, u = idx & 511;
  const float* g = gates + (size_t)b * 2048;
  float ig = sigf(g[u]), fg = sigf(g[512 + u]);
  float gg = tanhf(g[1024 + u]), og = sigf(g[1536 + u]);
  float cv = fg * c0[idx] + ig * gg;
  c[idx] = cv;
  h[idx] = og * tanhf(cv);
}

// ---------------- p_raw = c @ [W_addr(560)|W_ea(512)]^T + bias : [256][1072]
__global__ __launch_bounds__(256) void gemm_heads_kernel(
    const float* __restrict__ C, const float* __restrict__ W_addr,
    const float* __restrict__ W_ea, const float* __restrict__ b_addr,
    const float* __restrict__ b_ea, float* __restrict__ p_raw) {
  __shared__ float As[16][33];
  __shared__ float Ws[16][65];
  int tid = threadIdx.x, tx = tid & 15, ty = tid >> 4;
  int row0 = blockIdx.y * 32, col0 = blockIdx.x * 64;
  float acc[2][4] = {{0,0,0,0},{0,0,0,0}};
  for (int k0 = 0; k0 < 512; k0 += 16) {
    for (int i = tid; i < 32 * 16; i += 256) {
      int rr = i >> 4, cc = i & 15;
      As[cc][rr] = C[(size_t)(row0 + rr) * 512 + k0 + cc];
    }
    for (int i = tid; i < 64 * 16; i += 256) {
      int rr = i >> 4, cc = i & 15;
      int col = col0 + rr;
      float v = 0.f;
      if (col < 560) v = W_addr[(size_t)col * 512 + k0 + cc];
      else if (col < 1072) v = W_ea[(size_t)(col - 560) * 512 + k0 + cc];
      Ws[cc][rr] = v;
    }
    __syncthreads();
#pragma unroll
    for (int kk = 0; kk < 16; kk++) {
      float a0 = As[kk][ty * 2 + 0], a1 = As[kk][ty * 2 + 1];
      float w0 = Ws[kk][tx * 4 + 0], w1 = Ws[kk][tx * 4 + 1];
      float w2 = Ws[kk][tx * 4 + 2], w3 = Ws[kk][tx * 4 + 3];
      acc[0][0] += a0 * w0; acc[0][1] += a0 * w1; acc[0][2] += a0 * w2; acc[0][3] += a0 * w3;
      acc[1][0] += a1 * w0; acc[1][1] += a1 * w1; acc[1][2] += a1 * w2; acc[1][3] += a1 * w3;
    }
    __syncthreads();
  }
  for (int i = 0; i < 2; i++)
    for (int j = 0; j < 4; j++) {
      int col = col0 + tx * 4 + j;
      if (col < 1072) {
        float bias = col < 560 ? b_addr[col] : b_ea[col - 560];
        p_raw[(size_t)(row0 + ty * 2 + i) * 1072 + col] = acc[i][j] + bias;
      }
    }
}

// ---------------- unpack head params
__global__ void head_params_kernel(const float* __restrict__ p_raw,
    float* __restrict__ kvec, float* __restrict__ knorm,
    float* __restrict__ betav, float* __restrict__ gatev,
    float* __restrict__ sv, float* __restrict__ gammav,
    float* __restrict__ evec, float* __restrict__ avec) {
  int hi = blockIdx.x, b = blockIdx.y, t = threadIdx.x;
  const float* p = p_raw + (size_t)b * 1072 + hi * 70;
  if (t < 64) {
    float kvv = tanhf(p[t]);
    kvec[((size_t)hi * 256 + b) * 64 + t] = kvv;
    float s = kvv * kvv;
    for (int m = 1; m < 64; m <<= 1) s += __shfl_xor(s, m);
    if (t == 0) {
      int hb = hi * 256 + b;
      knorm[hb] = sqrtf(s);
      betav[hb] = softplusf(p[64]);
      gatev[hb] = sigf(p[65]);
      float a0 = p[66], a1 = p[67], a2 = p[68];
      float mm = fmaxf(a0, fmaxf(a1, a2));
      float e0 = expf(a0 - mm), e1 = expf(a1 - mm), e2 = expf(a2 - mm);
      float es = e0 + e1 + e2;
      sv[hb * 3 + 0] = e0 / es; sv[hb * 3 + 1] = e1 / es; sv[hb * 3 + 2] = e2 / es;
      gammav[hb] = 1.0f + softplusf(p[69]);
    }
  } else if ((hi & 1) && hi < 7) {      // write heads 1,3,5 -> slots 0,1,2 (head 7 dead)
    int wj = hi >> 1, t2 = t - 64;
    const float* ea = p_raw + (size_t)b * 1072 + 560 + wj * 128;
    evec[((size_t)wj * 256 + b) * 64 + t2] = sigf(ea[t2]);
    avec[((size_t)wj * 256 + b) * 64 + t2] = tanhf(ea[64 + t2]);
  }
}

// ---------------- combo vectors + per-b scalars
// slots [20][B][64]:
//  0:k0 1:k1 2:k2 3:e1k2 4:k3 5:e1k3 6:a1 7:e1a1 8:e1 9:e1^2
//  10:k4 11:k5 12:k6 13:e5k6 14:a5 15:e5a5 16:e5 17:e5^2 18:e3 19:a3
// scal[b*8+]: 0:a1.k2 1:a1.k3 2:a1.a1 3:a5.k6 4:a5.a5
__global__ void combo_kernel(const float* __restrict__ kvec,
                             const float* __restrict__ evec,
                             const float* __restrict__ avec,
                             float* __restrict__ combo, float* __restrict__ scal) {
  int b = blockIdx.x, m = threadIdx.x;
  size_t bm = (size_t)b * 64 + m;
  float k0 = kvec[0 * 16384 + bm], k1 = kvec[1 * 16384 + bm];
  float k2 = kvec[2 * 16384 + bm], k3 = kvec[3 * 16384 + bm];
  float k4 = kvec[4 * 16384 + bm], k5 = kvec[5 * 16384 + bm];
  float k6 = kvec[6 * 16384 + bm];
  float e1 = evec[0 * 16384 + bm], a1 = avec[0 * 16384 + bm];
  float e3 = evec[1 * 16384 + bm], a3 = avec[1 * 16384 + bm];
  float e5 = evec[2 * 16384 + bm], a5 = avec[2 * 16384 + bm];
  combo[0 * 16384 + bm] = k0;  combo[1 * 16384 + bm] = k1;
  combo[2 * 16384 + bm] = k2;  combo[3 * 16384 + bm] = e1 * k2;
  combo[4 * 16384 + bm] = k3;  combo[5 * 16384 + bm] = e1 * k3;
  combo[6 * 16384 + bm] = a1;  combo[7 * 16384 + bm] = e1 * a1;
  combo[8 * 16384 + bm] = e1;  combo[9 * 16384 + bm] = e1 * e1;
  combo[10 * 16384 + bm] = k4; combo[11 * 16384 + bm] = k5;
  combo[12 * 16384 + bm] = k6; combo[13 * 16384 + bm] = e5 * k6;
  combo[14 * 16384 + bm] = a5; combo[15 * 16384 + bm] = e5 * a5;
  combo[16 * 16384 + bm] = e5; combo[17 * 16384 + bm] = e5 * e5;
  combo[18 * 16384 + bm] = e3; combo[19 * 16384 + bm] = a3;
  float s0 = a1 * k2, s1 = a1 * k3, s2 = a1 * a1, s3 = a5 * k6, s4 = a5 * a5;
#pragma unroll
  for (int d = 1; d < 64; d <<= 1) {
    s0 += __shfl_xor(s0, d); s1 += __shfl_xor(s1, d); s2 += __shfl_xor(s2, d);
    s3 += __shfl_xor(s3, d); s4 += __shfl_xor(s4, d);
  }
  if (m == 0) {
    scal[b * 8 + 0] = s0; scal[b * 8 + 1] = s1; scal[b * 8 + 2] = s2;
    scal[b * 8 + 3] = s3; scal[b * 8 + 4] = s4;
  }
}

#define LDC(j, q) (*(const float4*)(cb + (size_t)(j) * 16384 + (q) * 4))

// ---------------- pass 1: fp32 mem -> bf16 shadow copy + 9 planes
// P1: [sc0, sc1, Da2, Dbc2, Da3, Dbc3, S0, T1, T2]
__global__ __launch_bounds__(256) void dotpass1_kernel(
    const float* __restrict__ mem, const float* __restrict__ combo,
    const float* __restrict__ knorm, const float* __restrict__ betav,
    const float* __restrict__ scal, float* __restrict__ P1,
    unsigned short* __restrict__ mem_bf) {
  extern __shared__ float4 tile[];
  const int NN = 4096;
  int b = blockIdx.y, n0 = blockIdx.x * 256, tid = threadIdx.x;
  const float4* m4 = (const float4*)mem + ((size_t)b * NN + n0) * 16;
  ushort4* mb4 = (ushort4*)mem_bf + ((size_t)b * NN + n0) * 16;
#pragma unroll
  for (int i = 0; i < 16; i++) {
    int L = tid + i * 256, r = L >> 4, q = L & 15;
    float4 v = m4[L];
    tile[r * 16 + (q ^ (r & 15))] = v;
    ushort4 o;
    o.x = f2bf(v.x); o.y = f2bf(v.y); o.z = f2bf(v.z); o.w = f2bf(v.w);
    mb4[L] = o;
  }
  __syncthreads();
  const float* cb = combo + (size_t)b * 64;
  float d0=0,d1=0,d2=0,d3=0,d4=0,d5=0,d6=0,d7=0,s0=0,s1=0,s2=0;
#pragma unroll
  for (int q = 0; q < 16; q++) {
    float4 v = tile[tid * 16 + (q ^ (tid & 15))];
    float4 sq = make_float4(v.x*v.x, v.y*v.y, v.z*v.z, v.w*v.w);
    d0 += dot4(v, LDC(0, q)); d1 += dot4(v, LDC(1, q));
    d2 += dot4(v, LDC(2, q)); d3 += dot4(v, LDC(3, q));
    d4 += dot4(v, LDC(4, q)); d5 += dot4(v, LDC(5, q));
    d6 += dot4(v, LDC(6, q)); d7 += dot4(v, LDC(7, q));
    s0 += sq.x + sq.y + sq.z + sq.w;
    s1 += dot4(sq, LDC(8, q)); s2 += dot4(sq, LDC(9, q));
  }
  float kn0 = knorm[0 * 256 + b], be0 = betav[0 * 256 + b];
  float kn1 = knorm[1 * 256 + b], be1 = betav[1 * 256 + b];
  float cak2 = scal[b * 8 + 0], cak3 = scal[b * 8 + 1], caa = scal[b * 8 + 2];
  float rn = sqrtf(s0);
  size_t o = (size_t)b * NN + n0 + tid;
  P1[0*PLANE+o] = be0 * d0 / (rn * kn0 + EPSF);
  P1[1*PLANE+o] = be1 * d1 / (rn * kn1 + EPSF);
  P1[2*PLANE+o] = d2; P1[3*PLANE+o] = d3 - cak2;
  P1[4*PLANE+o] = d4; P1[5*PLANE+o] = d5 - cak3;
  P1[6*PLANE+o] = s0; P1[7*PLANE+o] = s1 - d6; P1[8*PLANE+o] = s2 - 2.f*d7 + caa;
}

// ---------------- pass 2: bf16 mem -> m2 in regs, 7 planes
// P2: [sc4, sc5, Da6, Dbc6, S0, T1, T2]
__global__ __launch_bounds__(256) void dotpass2_kernel(
    const unsigned short* __restrict__ mem_bf, const float* __restrict__ combo,
    const float* __restrict__ w_all, const float* __restrict__ knorm,
    const float* __restrict__ betav, const float* __restrict__ scal,
    float* __restrict__ P2) {
  __shared__ uint4 tileb[2048];   // 256 rows x 8 granules(16B) = 32 KB
  const int NN = 4096;
  int b = blockIdx.y, n0 = blockIdx.x * 256, tid = threadIdx.x;
  size_t bo = (size_t)b * NN;
  const uint4* mb = (const uint4*)mem_bf + (bo + n0) * 8;
#pragma unroll
  for (int i = 0; i < 8; i++) {
    int G = tid + i * 256, r = G >> 3, g = G & 7;
    tileb[r * 8 + (g ^ (r & 7))] = mb[G];
  }
  __syncthreads();
  const float* cb = combo + (size_t)b * 64;
  float u1 = w_all[1 * PLANE + bo + n0 + tid];
  float u3 = w_all[3 * PLANE + bo + n0 + tid];
  float t0=0,t1=0,t2=0,t3=0,t4=0,t5=0,r0=0,r1=0,r2=0;
#pragma unroll
  for (int g = 0; g < 8; g++) {
    uint4 uv = tileb[tid * 8 + (g ^ (tid & 7))];
#pragma unroll
    for (int h = 0; h < 2; h++) {
      unsigned int pa = h ? uv.z : uv.x;
      unsigned int pb = h ? uv.w : uv.y;
      float4 v;
      v.x = bf2f(pa & 0xFFFFu); v.y = bf2f(pa >> 16);
      v.z = bf2f(pb & 0xFFFFu); v.w = bf2f(pb >> 16);
      int q = g * 2 + h;
      float4 e1 = LDC(8, q), aa1 = LDC(6, q), e3 = LDC(18, q), aa3 = LDC(19, q);
      float4 m1, m2;
      m1.x = v.x * (1.f - u1 * e1.x) + u1 * aa1.x;
      m1.y = v.y * (1.f - u1 * e1.y) + u1 * aa1.y;
      m1.z = v.z * (1.f - u1 * e1.z) + u1 * aa1.z;
      m1.w = v.w * (1.f - u1 * e1.w) + u1 * aa1.w;
      m2.x = m1.x * (1.f - u3 * e3.x) + u3 * aa3.x;
      m2.y = m1.y * (1.f - u3 * e3.y) + u3 * aa3.y;
      m2.z = m1.z * (1.f - u3 * e3.z) + u3 * aa3.z;
      m2.w = m1.w * (1.f - u3 * e3.w) + u3 * aa3.w;
      float4 sq = make_float4(m2.x*m2.x, m2.y*m2.y, m2.z*m2.z, m2.w*m2.w);
      t0 += dot4(m2, LDC(10, q)); t1 += dot4(m2, LDC(11, q));
      t2 += dot4(m2, LDC(12, q)); t3 += dot4(m2, LDC(13, q));
      t4 += dot4(m2, LDC(14, q)); t5 += dot4(m2, LDC(15, q));
      r0 += sq.x + sq.y + sq.z + sq.w;
      r1 += dot4(sq, LDC(16, q)); r2 += dot4(sq, LDC(17, q));
    }
  }
  float kn4 = knorm[4 * 256 + b], be4 = betav[4 * 256 + b];
  float kn5 = knorm[5 * 256 + b], be5 = betav[5 * 256 + b];
  float cak6 = scal[b * 8 + 3], caa6 = scal[b * 8 + 4];
  float rn = sqrtf(r0);
  size_t o = bo + n0 + tid;
  P2[0*PLANE+o] = be4 * t0 / (rn * kn4 + EPSF);
  P2[1*PLANE+o] = be5 * t1 / (rn * kn5 + EPSF);
  P2[2*PLANE+o] = t2; P2[3*PLANE+o] = t3 - cak6;
  P2[4*PLANE+o] = r0; P2[5*PLANE+o] = r1 - t4; P2[6*PLANE+o] = r2 - 2.f*t5 + caa6;
}

// ---------------- read pass: all four reads from bf16 mem + w planes
__global__ __launch_bounds__(256) void readpass_kernel(
    const unsigned short* __restrict__ mem_bf, const float* __restrict__ w_all,
    const float* __restrict__ evec, const float* __restrict__ avec,
    float* __restrict__ reads) {
  const int NN = 4096;
  int b = blockIdx.y, n0 = blockIdx.x * 256, tid = threadIdx.x;
  int wv = tid >> 6, lane = tid & 63, q = lane & 15, rl = lane >> 4;
  size_t bo = (size_t)b * NN;
  float4 e1 = *(const float4*)(evec + 0 * 16384 + b * 64 + q * 4);
  float4 a1 = *(const float4*)(avec + 0 * 16384 + b * 64 + q * 4);
  float4 e3 = *(const float4*)(evec + 1 * 16384 + b * 64 + q * 4);
  float4 a3 = *(const float4*)(avec + 1 * 16384 + b * 64 + q * 4);
  float4 e5 = *(const float4*)(evec + 2 * 16384 + b * 64 + q * 4);
  float4 a5 = *(const float4*)(avec + 2 * 16384 + b * 64 + q * 4);
  const float* w0r = w_all + 0 * PLANE + bo;
  const float* w1r = w_all + 1 * PLANE + bo;
  const float* w2r = w_all + 2 * PLANE + bo;
  const float* w3r = w_all + 3 * PLANE + bo;
  const float* w4r = w_all + 4 * PLANE + bo;
  const float* w5r = w_all + 5 * PLANE + bo;
  const float* w6r = w_all + 6 * PLANE + bo;
  __shared__ float sred[4][4][16][4];   // [read][wave][q][comp]
  const ushort4* mb = (const ushort4*)mem_bf;
  float A[4][4] = {{0,0,0,0},{0,0,0,0},{0,0,0,0},{0,0,0,0}};
#pragma unroll 4
  for (int t = 0; t < 16; t++) {
    int nl = wv * 64 + t * 4 + rl, n = n0 + nl;
    ushort4 uv = mb[(bo + n0 + (size_t)nl) * 16 + q];
    float vx = bf2f(uv.x), vy = bf2f(uv.y), vz = bf2f(uv.z), vw = bf2f(uv.w);
    float w0v = w0r[n], u1 = w1r[n], w2v = w2r[n], u3 = w3r[n];
    float w4v = w4r[n], u5 = w5r[n], w6v = w6r[n];
    A[0][0] += w0v * vx; A[0][1] += w0v * vy; A[0][2] += w0v * vz; A[0][3] += w0v * vw;
    float m1x = vx * (1.f - u1 * e1.x) + u1 * a1.x;
    float m1y = vy * (1.f - u1 * e1.y) + u1 * a1.y;
    float m1z = vz * (1.f - u1 * e1.z) + u1 * a1.z;
    float m1w = vw * (1.f - u1 * e1.w) + u1 * a1.w;
    A[1][0] += w2v * m1x; A[1][1] += w2v * m1y; A[1][2] += w2v * m1z; A[1][3] += w2v * m1w;
    float m2x = m1x * (1.f - u3 * e3.x) + u3 * a3.x;
    float m2y = m1y * (1.f - u3 * e3.y) + u3 * a3.y;
    float m2z = m1z * (1.f - u3 * e3.z) + u3 * a3.z;
    float m2w = m1w * (1.f - u3 * e3.w) + u3 * a3.w;
    A[2][0] += w4v * m2x; A[2][1] += w4v * m2y; A[2][2] += w4v * m2z; A[2][3] += w4v * m2w;
    float m3x = m2x * (1.f - u5 * e5.x) + u5 * a5.x;
    float m3y = m2y * (1.f - u5 * e5.y) + u5 * a5.y;
    float m3z = m2z * (1.f - u5 * e5.z) + u5 * a5.z;
    float m3w = m2w * (1.f - u5 * e5.w) + u5 * a5.w;
    A[3][0] += w6v * m3x; A[3][1] += w6v * m3y; A[3][2] += w6v * m3z; A[3][3] += w6v * m3w;
  }
#pragma unroll
  for (int j = 0; j < 4; j++)
#pragma unroll
    for (int cmp = 0; cmp < 4; cmp++) {
      float x = A[j][cmp];
#pragma unroll
      for (int m = 16; m < 64; m <<= 1) x += __shfl_xor(x, m);
      A[j][cmp] = x;
    }
  if (rl == 0)
#pragma unroll
    for (int j = 0; j < 4; j++) {
      sred[j][wv][q][0] = A[j][0]; sred[j][wv][q][1] = A[j][1];
      sred[j][wv][q][2] = A[j][2]; sred[j][wv][q][3] = A[j][3];
    }
  __syncthreads();
  if (tid < 64) {
    int qq = tid >> 2, cc = tid & 3;
#pragma unroll
    for (int j = 0; j < 4; j++) {
      float s = sred[j][0][qq][cc] + sred[j][1][qq][cc] + sred[j][2][qq][cc] + sred[j][3][qq][cc];
      atomicAdd(&reads[j * 16384 + b * 64 + qq * 4 + cc], s);
    }
  }
}

// ---------------- addressing chain (unified): ND direct slots then NE expanded slots
template<int ND, int NE>
__global__ __launch_bounds__(256) void chain_kernel(
    const float* __restrict__ P, const float* __restrict__ uplane,
    const float* __restrict__ knorm, const float* __restrict__ betav,
    const float* __restrict__ gatev, const float* __restrict__ sv,
    const float* __restrict__ gammav, const float* __restrict__ prev_w,
    float* __restrict__ w_all, int head_base) {
  const int NN = 4096, BB = 256;
  int slot = blockIdx.x, b = blockIdx.y;
  int head = head_base + slot;
  size_t bo = (size_t)b * NN;
  __shared__ float wg[4096];
  __shared__ float redm[4], reds[4], reds2[4];
  int tid = threadIdx.x;
  int lane = tid & 63, wv = tid >> 6;
  int hb = head * BB + b;
  float kn = knorm[hb], be = betav[hb], ga = gatev[hb], gm = gammav[hb];
  float s0 = sv[hb * 3 + 0], s1 = sv[hb * 3 + 1], s2 = sv[hb * 3 + 2];
  const float* SC  = P + (size_t)slot * PLANE;
  const float* Da  = P + (size_t)(ND + 2 * (slot - ND)) * PLANE;
  const float* Dbc = Da + PLANE;
  const float* S0p = P + (size_t)(ND + 2 * NE) * PLANE;
  const float* T1p = S0p + PLANE;
  const float* T2p = T1p + PLANE;

  float sc[16];
  float mx = -1e30f;
#pragma unroll
  for (int i = 0; i < 16; i++) {
    int n = tid + i * 256;
    float scv;
    if (slot < ND) {
      scv = SC[bo + n];
    } else {
      float u = uplane[bo + n];
      float d = Da[bo + n] - u * Dbc[bo + n];
      float nn2 = S0p[bo + n] - 2.f * u * T1p[bo + n] + u * u * T2p[bo + n];
      nn2 = fmaxf(nn2, 0.f);
      scv = be * d / (sqrtf(nn2) * kn + EPSF);
    }
    sc[i] = scv;
    mx = fmaxf(mx, scv);
  }
  for (int m = 1; m < 64; m <<= 1) mx = fmaxf(mx, __shfl_xor(mx, m));
  if (lane == 0) redm[wv] = mx;
  __syncthreads();
  mx = fmaxf(fmaxf(redm[0], redm[1]), fmaxf(redm[2], redm[3]));
  float sum = 0.f;
#pragma unroll
  for (int i = 0; i < 16; i++) { sc[i] = expf(sc[i] - mx); sum += sc[i]; }
  for (int m = 1; m < 64; m <<= 1) sum += __shfl_xor(sum, m);
  if (lane == 0) reds[wv] = sum;
  __syncthreads();
  sum = reds[0] + reds[1] + reds[2] + reds[3];
  float inv = 1.0f / sum;
  const float* pw = prev_w + (size_t)head * BB * NN + bo;
#pragma unroll
  for (int i = 0; i < 16; i++) {
    int n = tid + i * 256;
    wg[n] = ga * (sc[i] * inv) + (1.f - ga) * pw[n];
  }
  __syncthreads();
  float wp[16];
  float sum2 = 0.f;
#pragma unroll
  for (int i = 0; i < 16; i++) {
    int n = tid + i * 256;
    float wsv = s0 * wg[(n + NN - 1) & (NN - 1)] + s1 * wg[n] + s2 * wg[(n + 1) & (NN - 1)];
    wp[i] = powf(wsv, gm);
    sum2 += wp[i];
  }
  for (int m = 1; m < 64; m <<= 1) sum2 += __shfl_xor(sum2, m);
  if (lane == 0) reds2[wv] = sum2;
  __syncthreads();
  sum2 = reds2[0] + reds2[1] + reds2[2] + reds2[3];
  float invs = 1.0f / (sum2 + EPSF);
  float* wo = w_all + (size_t)head * BB * NN + bo;
#pragma unroll
  for (int i = 0; i < 16; i++) wo[tid + i * 256] = wp[i] * invs;
}

// ---------------- out = sigmoid([h|reads] @ W_out^T + b_out) : [256][64]
__global__ __launch_bounds__(256) void gemm_out_kernel(
    const float* __restrict__ h, const float* __restrict__ reads,
    const float* __restrict__ W_out, const float* __restrict__ b_out,
    float* __restrict__ out) {
  __shared__ float As[16][33];
  __shared__ float Ws[16][65];
  int tid = threadIdx.x, tx = tid & 15, ty = tid >> 4;
  int row0 = blockIdx.y * 32;
  float acc[2][4] = {{0,0,0,0},{0,0,0,0}};
  for (int k0 = 0; k0 < 768; k0 += 16) {
    for (int i = tid; i < 32 * 16; i += 256) {
      int rr = i >> 4, cc = i & 15;
      int row = row0 + rr, k = k0 + cc;
      float v;
      if (k < 512) v = h[row * 512 + k];
      else { int slot = (k - 512) >> 6, m = (k - 512) & 63; v = reads[((size_t)slot * 256 + row) * 64 + m]; }
      As[cc][rr] = v;
    }
    for (int i = tid; i < 64 * 16; i += 256) {
      int rr = i >> 4, cc = i & 15;
      Ws[cc][rr] = W_out[(size_t)rr * 768 + k0 + cc];
    }
    __syncthreads();
#pragma unroll
    for (int kk = 0; kk < 16; kk++) {
      float a0 = As[kk][ty * 2 + 0], a1 = As[kk][ty * 2 + 1];
      float w0 = Ws[kk][tx * 4 + 0], w1 = Ws[kk][tx * 4 + 1];
      float w2 = Ws[kk][tx * 4 + 2], w3 = Ws[kk][tx * 4 + 3];
      acc[0][0] += a0 * w0; acc[0][1] += a0 * w1; acc[0][2] += a0 * w2; acc[0][3] += a0 * w3;
      acc[1][0] += a1 * w0; acc[1][1] += a1 * w1; acc[1][2] += a1 * w2; acc[1][3] += a1 * w3;
    }
    __syncthreads();
  }
  for (int i = 0; i < 2; i++)
    for (int j = 0; j < 4; j++) {
      int cc = tx * 4 + j;
      out[(size_t)(row0 + ty * 2 + i) * 64 + cc] = sigf(acc[i][j] + b_out[cc]);
    }
}

extern "C" void kernel_launch(void* const* d_in, const int* in_sizes, int n_in,
                              void* d_out, int out_size, void* d_ws, size_t ws_size,
                              hipStream_t stream) {
  const float* in_data = (const float*)d_in[0];
  const float* memory  = (const float*)d_in[1];
  const float* h0      = (const float*)d_in[2];
  const float* c0      = (const float*)d_in[3];
  const float* prev_w  = (const float*)d_in[4];
  const float* prev_r  = (const float*)d_in[5];
  const float* W_ih    = (const float*)d_in[6];
  const float* b_ih    = (const float*)d_in[7];
  const float* W_hh    = (const float*)d_in[8];
  const float* b_hh    = (const float*)d_in[9];
  const float* W_out   = (const float*)d_in[10];
  const float* b_out   = (const float*)d_in[11];
  const float* W_addr  = (const float*)d_in[12];
  const float* b_addr  = (const float*)d_in[13];
  const float* W_ea    = (const float*)d_in[14];
  const float* b_ea    = (const float*)d_in[15];
  float* out = (float*)d_out;
  (void)in_sizes; (void)n_in; (void)out_size; (void)ws_size;

  float* ws = (float*)d_ws;
  size_t off = 0;
  auto alloc = [&](size_t n) { float* p = ws + off; off += (n + 63) & ~(size_t)63; return p; };
  float* gates  = alloc(256 * 2048);
  float* cbuf   = alloc(256 * 512);
  float* hbuf   = alloc(256 * 512);
  float* p_raw  = alloc(256 * 1072);
  float* kvec   = alloc(8 * 256 * 64);
  float* knorm  = alloc(8 * 256);
  float* betav  = alloc(8 * 256);
  float* gatev  = alloc(8 * 256);
  float* sv     = alloc(8 * 256 * 3);
  float* gammav = alloc(8 * 256);
  float* evec   = alloc(3 * 256 * 64);
  float* avec   = alloc(3 * 256 * 64);
  float* combo  = alloc(20 * 256 * 64);
  float* scal   = alloc(256 * 8);
  float* P1     = alloc(9 * PLANE);
  float* P2     = alloc(7 * PLANE);
  float* w_all  = alloc(7 * PLANE);
  float* reads  = alloc(4 * 256 * 64);
  unsigned short* mem_bf = (unsigned short*)alloc(33554432); // 256*4096*64 bf16 = 128 MB

  hipMemsetAsync(reads, 0, 4 * 256 * 64 * sizeof(float), stream);

  gemm_gates_kernel<<<dim3(32, 8), 256, 0, stream>>>(in_data, prev_r, h0, W_ih, W_hh, b_ih, b_hh, gates);
  lstm_elem_kernel<<<(256 * 512 + 255) / 256, 256, 0, stream>>>(gates, c0, cbuf, hbuf);
  gemm_heads_kernel<<<dim3(17, 8), 256, 0, stream>>>(cbuf, W_addr, W_ea, b_addr, b_ea, p_raw);
  head_params_kernel<<<dim3(8, 256), 128, 0, stream>>>(p_raw, kvec, knorm, betav, gatev, sv, gammav, evec, avec);
  combo_kernel<<<256, 64, 0, stream>>>(kvec, evec, avec, combo, scal);

  dim3 pgrid(16, 256);
  dotpass1_kernel<<<pgrid, 256, 65536, stream>>>(memory, combo, knorm, betav, scal, P1, mem_bf);
  chain_kernel<2, 2><<<dim3(4, 256), 256, 0, stream>>>(
      P1, w_all + 1 * PLANE, knorm, betav, gatev, sv, gammav, prev_w, w_all, 0);
  dotpass2_kernel<<<pgrid, 256, 0, stream>>>(mem_bf, combo, w_all, knorm, betav, scal, P2);
  chain_kernel<2, 1><<<dim3(3, 256), 256, 0, stream>>>(
      P2, w_all + 5 * PLANE, knorm, betav, gatev, sv, gammav, prev_w, w_all, 4);
  readpass_kernel<<<pgrid, 256, 0, stream>>>(mem_bf, w_all, evec, avec, reads);

  gemm_out_kernel<<<dim3(1, 8), 256, 0, stream>>>(hbuf, reads, W_out, b_out, out);
}

// Round 4
// 899.145 us; speedup vs baseline: 1.1250x; 1.0253x over previous
//
#include <hip/hip_runtime.h>
#include <hip/hip_fp16.h>
#include <math.h>

#define EPSF 1e-8f
#define NN 4096
#define BB 256
#define PH ((size_t)BB * NN)

__device__ __forceinline__ float sigf(float x) { return 1.0f / (1.0f + expf(-x)); }
__device__ __forceinline__ float softplusf(float x) { return x > 20.0f ? x : log1pf(expf(x)); }
__device__ __forceinline__ float dot4(float4 a, float4 b) {
  return a.x * b.x + a.y * b.y + a.z * b.z + a.w * b.w;
}
__device__ __forceinline__ unsigned short f2bf(float x) {
  unsigned int u = __float_as_uint(x);
  unsigned int r = (u + 0x7FFF + ((u >> 16) & 1)) >> 16;
  return (unsigned short)r;
}
__device__ __forceinline__ float bf2f(unsigned int lo16) {
  return __uint_as_float(lo16 << 16);
}

// ---------------- gates = [in|prev_reads|h0] @ [W_ih|W_hh]^T + b_ih + b_hh : [256][2048]
__device__ __forceinline__ float gather_x(const float* __restrict__ in_data,
                                          const float* __restrict__ prev_reads,
                                          const float* __restrict__ h0,
                                          int row, int k) {
  if (k < 64) return in_data[row * 64 + k];
  if (k < 320) { int i = (k - 64) >> 6, m = (k - 64) & 63; return prev_reads[((size_t)i * 256 + row) * 64 + m]; }
  return h0[row * 512 + (k - 320)];
}

__global__ __launch_bounds__(256) void gemm_gates_kernel(
    const float* __restrict__ in_data, const float* __restrict__ prev_reads,
    const float* __restrict__ h0, const float* __restrict__ W_ih,
    const float* __restrict__ W_hh, const float* __restrict__ b_ih,
    const float* __restrict__ b_hh, float* __restrict__ gates) {
  __shared__ float As[16][33];
  __shared__ float Ws[16][65];
  int tid = threadIdx.x, tx = tid & 15, ty = tid >> 4;
  int row0 = blockIdx.y * 32, col0 = blockIdx.x * 64;
  float acc[2][4] = {{0,0,0,0},{0,0,0,0}};
  for (int k0 = 0; k0 < 832; k0 += 16) {
    const float* Wp; int kw, KW;
    if (k0 < 320) { Wp = W_ih; kw = k0; KW = 320; }
    else          { Wp = W_hh; kw = k0 - 320; KW = 512; }
    for (int i = tid; i < 32 * 16; i += 256) {
      int rr = i >> 4, cc = i & 15;
      As[cc][rr] = gather_x(in_data, prev_reads, h0, row0 + rr, k0 + cc);
    }
    for (int i = tid; i < 64 * 16; i += 256) {
      int rr = i >> 4, cc = i & 15;
      Ws[cc][rr] = Wp[(size_t)(col0 + rr) * KW + kw + cc];
    }
    __syncthreads();
#pragma unroll
    for (int kk = 0; kk < 16; kk++) {
      float a0 = As[kk][ty * 2 + 0], a1 = As[kk][ty * 2 + 1];
      float w0 = Ws[kk][tx * 4 + 0], w1 = Ws[kk][tx * 4 + 1];
      float w2 = Ws[kk][tx * 4 + 2], w3 = Ws[kk][tx * 4 + 3];
      acc[0][0] += a0 * w0; acc[0][1] += a0 * w1; acc[0][2] += a0 * w2; acc[0][3] += a0 * w3;
      acc[1][0] += a1 * w0; acc[1][1] += a1 * w1; acc[1][2] += a1 * w2; acc[1][3] += a1 * w3;
    }
    __syncthreads();
  }
  for (int i = 0; i < 2; i++)
    for (int j = 0; j < 4; j++) {
      int cc = col0 + tx * 4 + j;
      gates[(size_t)(row0 + ty * 2 + i) * 2048 + cc] = acc[i][j] + b_ih[cc] + b_hh[cc];
    }
}

__global__ void lstm_elem_kernel(const float* __restrict__ gates,
                                 const float* __restrict__ c0,
                                 float* __restrict__ c, float* __restrict__ h) {
  int idx = blockIdx.x * 256 + threadIdx.x;
  if (idx >= 256 * 512) return;
  int b = idx >> 9, u = idx & 511;
  const float* g = gates + (size_t)b * 2048;
  float ig = sigf(g[u]), fg = sigf(g[512 + u]);
  float gg = tanhf(g[1024 + u]), og = sigf(g[1536 + u]);
  float cv = fg * c0[idx] + ig * gg;
  c[idx] = cv;
  h[idx] = og * tanhf(cv);
}

// ---------------- p_raw = c @ [W_addr(560)|W_ea(512)]^T + bias : [256][1072]
__global__ __launch_bounds__(256) void gemm_heads_kernel(
    const float* __restrict__ C, const float* __restrict__ W_addr,
    const float* __restrict__ W_ea, const float* __restrict__ b_addr,
    const float* __restrict__ b_ea, float* __restrict__ p_raw) {
  __shared__ float As[16][33];
  __shared__ float Ws[16][65];
  int tid = threadIdx.x, tx = tid & 15, ty = tid >> 4;
  int row0 = blockIdx.y * 32, col0 = blockIdx.x * 64;
  float acc[2][4] = {{0,0,0,0},{0,0,0,0}};
  for (int k0 = 0; k0 < 512; k0 += 16) {
    for (int i = tid; i < 32 * 16; i += 256) {
      int rr = i >> 4, cc = i & 15;
      As[cc][rr] = C[(size_t)(row0 + rr) * 512 + k0 + cc];
    }
    for (int i = tid; i < 64 * 16; i += 256) {
      int rr = i >> 4, cc = i & 15;
      int col = col0 + rr;
      float v = 0.f;
      if (col < 560) v = W_addr[(size_t)col * 512 + k0 + cc];
      else if (col < 1072) v = W_ea[(size_t)(col - 560) * 512 + k0 + cc];
      Ws[cc][rr] = v;
    }
    __syncthreads();
#pragma unroll
    for (int kk = 0; kk < 16; kk++) {
      float a0 = As[kk][ty * 2 + 0], a1 = As[kk][ty * 2 + 1];
      float w0 = Ws[kk][tx * 4 + 0], w1 = Ws[kk][tx * 4 + 1];
      float w2 = Ws[kk][tx * 4 + 2], w3 = Ws[kk][tx * 4 + 3];
      acc[0][0] += a0 * w0; acc[0][1] += a0 * w1; acc[0][2] += a0 * w2; acc[0][3] += a0 * w3;
      acc[1][0] += a1 * w0; acc[1][1] += a1 * w1; acc[1][2] += a1 * w2; acc[1][3] += a1 * w3;
    }
    __syncthreads();
  }
  for (int i = 0; i < 2; i++)
    for (int j = 0; j < 4; j++) {
      int col = col0 + tx * 4 + j;
      if (col < 1072) {
        float bias = col < 560 ? b_addr[col] : b_ea[col - 560];
        p_raw[(size_t)(row0 + ty * 2 + i) * 1072 + col] = acc[i][j] + bias;
      }
    }
}

// ---------------- per-b params: knorm/beta/gate/s/gamma + combo vectors + scalars
// combo slots [20][256][64]:
//  0:k0 1:k1 2:k2 3:e1k2 4:k3 5:e1k3 6:a1 7:e1a1 8:e1 9:e1^2
//  10:k4 11:k5 12:k6 13:e5k6 14:a5 15:e5a5 16:e5 17:e5^2 18:e3 19:a3
// scal[b*8+]: 0:a1.k2 1:a1.k3 2:a1.a1 3:a5.k6 4:a5.a5
__global__ void params_kernel(const float* __restrict__ p_raw,
    float* __restrict__ knorm, float* __restrict__ betav,
    float* __restrict__ gatev, float* __restrict__ sv,
    float* __restrict__ gammav, float* __restrict__ combo,
    float* __restrict__ scal) {
  int b = blockIdx.x, m = threadIdx.x;
  const float* p = p_raw + (size_t)b * 1072;
  float kv[7];
#pragma unroll
  for (int hi = 0; hi < 7; hi++) {
    float k = tanhf(p[hi * 70 + m]);
    kv[hi] = k;
    float s = k * k;
#pragma unroll
    for (int d = 1; d < 64; d <<= 1) s += __shfl_xor(s, d);
    if (m == 0) {
      int hb = hi * BB + b;
      knorm[hb] = sqrtf(s);
      betav[hb] = softplusf(p[hi * 70 + 64]);
      gatev[hb] = sigf(p[hi * 70 + 65]);
      float a0 = p[hi * 70 + 66], a1 = p[hi * 70 + 67], a2 = p[hi * 70 + 68];
      float mm = fmaxf(a0, fmaxf(a1, a2));
      float e0 = expf(a0 - mm), e1 = expf(a1 - mm), e2 = expf(a2 - mm);
      float es = e0 + e1 + e2;
      sv[hb * 3 + 0] = e0 / es; sv[hb * 3 + 1] = e1 / es; sv[hb * 3 + 2] = e2 / es;
      gammav[hb] = 1.0f + softplusf(p[hi * 70 + 69]);
    }
  }
  float e1 = sigf(p[560 + 0 * 128 + m]),  a1v = tanhf(p[560 + 0 * 128 + 64 + m]);
  float e3 = sigf(p[560 + 1 * 128 + m]),  a3v = tanhf(p[560 + 1 * 128 + 64 + m]);
  float e5 = sigf(p[560 + 2 * 128 + m]),  a5v = tanhf(p[560 + 2 * 128 + 64 + m]);
  size_t bm = (size_t)b * 64 + m;
  combo[0 * 16384 + bm] = kv[0];  combo[1 * 16384 + bm] = kv[1];
  combo[2 * 16384 + bm] = kv[2];  combo[3 * 16384 + bm] = e1 * kv[2];
  combo[4 * 16384 + bm] = kv[3];  combo[5 * 16384 + bm] = e1 * kv[3];
  combo[6 * 16384 + bm] = a1v;    combo[7 * 16384 + bm] = e1 * a1v;
  combo[8 * 16384 + bm] = e1;     combo[9 * 16384 + bm] = e1 * e1;
  combo[10 * 16384 + bm] = kv[4]; combo[11 * 16384 + bm] = kv[5];
  combo[12 * 16384 + bm] = kv[6]; combo[13 * 16384 + bm] = e5 * kv[6];
  combo[14 * 16384 + bm] = a5v;   combo[15 * 16384 + bm] = e5 * a5v;
  combo[16 * 16384 + bm] = e5;    combo[17 * 16384 + bm] = e5 * e5;
  combo[18 * 16384 + bm] = e3;    combo[19 * 16384 + bm] = a3v;
  float s0 = a1v * kv[2], s1 = a1v * kv[3], s2 = a1v * a1v, s3 = a5v * kv[6], s4 = a5v * a5v;
#pragma unroll
  for (int d = 1; d < 64; d <<= 1) {
    s0 += __shfl_xor(s0, d); s1 += __shfl_xor(s1, d); s2 += __shfl_xor(s2, d);
    s3 += __shfl_xor(s3, d); s4 += __shfl_xor(s4, d);
  }
  if (m == 0) {
    scal[b * 8 + 0] = s0; scal[b * 8 + 1] = s1; scal[b * 8 + 2] = s2;
    scal[b * 8 + 3] = s3; scal[b * 8 + 4] = s4;
  }
}

#define CL(j, q) (*(const float4*)(cb + (j) * 64 + (q) * 4))

// ---------------- addressing chain (device): score -> softmax -> interp -> shift -> sharpen -> w (LDS fp16)
__device__ void chain_dev(int tid, int b, int head,
    const __half* __restrict__ SC, const __half* __restrict__ Da,
    const __half* __restrict__ Dbc, const __half* __restrict__ S0p,
    const __half* __restrict__ T1p, const __half* __restrict__ T2p,
    const __half* w_h, int u_head, __half* w_out,
    float* wg, float* red,
    const float* __restrict__ knorm, const float* __restrict__ betav,
    const float* __restrict__ gatev, const float* __restrict__ sv,
    const float* __restrict__ gammav, const float* __restrict__ prev_w) {
  int lane = tid & 63, wv = tid >> 6;
  int hb = head * BB + b;
  float kn = knorm[hb], be = betav[hb], ga = gatev[hb], gm = gammav[hb];
  float s0 = sv[hb * 3 + 0], s1 = sv[hb * 3 + 1], s2 = sv[hb * 3 + 2];
  size_t bo = (size_t)b * NN;
  const float* pw = prev_w + (size_t)head * PH + bo;
  float sc[8];
  float mx = -1e30f;
#pragma unroll
  for (int i = 0; i < 8; i++) {
    int n = tid + i * 512;
    float scv;
    if (SC != nullptr) {
      scv = __half2float(SC[bo + n]);
    } else {
      float u = __half2float(w_h[u_head * NN + n]);
      float d = __half2float(Da[bo + n]) - u * __half2float(Dbc[bo + n]);
      float nn2 = __half2float(S0p[bo + n]) - 2.f * u * __half2float(T1p[bo + n])
                + u * u * __half2float(T2p[bo + n]);
      nn2 = fmaxf(nn2, 0.f);
      scv = be * d / (sqrtf(nn2) * kn + EPSF);
    }
    sc[i] = scv; mx = fmaxf(mx, scv);
  }
#pragma unroll
  for (int m = 1; m < 64; m <<= 1) mx = fmaxf(mx, __shfl_xor(mx, m));
  if (lane == 0) red[wv] = mx;
  __syncthreads();
  mx = red[0];
#pragma unroll
  for (int w = 1; w < 8; w++) mx = fmaxf(mx, red[w]);
  float sum = 0.f;
#pragma unroll
  for (int i = 0; i < 8; i++) { sc[i] = expf(sc[i] - mx); sum += sc[i]; }
#pragma unroll
  for (int m = 1; m < 64; m <<= 1) sum += __shfl_xor(sum, m);
  if (lane == 0) red[8 + wv] = sum;
  __syncthreads();
  sum = 0.f;
#pragma unroll
  for (int w = 0; w < 8; w++) sum += red[8 + w];
  float inv = 1.0f / sum;
#pragma unroll
  for (int i = 0; i < 8; i++) {
    int n = tid + i * 512;
    wg[n] = ga * (sc[i] * inv) + (1.f - ga) * pw[n];
  }
  __syncthreads();
  float wp[8];
  float sum2 = 0.f;
#pragma unroll
  for (int i = 0; i < 8; i++) {
    int n = tid + i * 512;
    float wsv = s0 * wg[(n + NN - 1) & (NN - 1)] + s1 * wg[n] + s2 * wg[(n + 1) & (NN - 1)];
    wp[i] = powf(wsv, gm);
    sum2 += wp[i];
  }
#pragma unroll
  for (int m = 1; m < 64; m <<= 1) sum2 += __shfl_xor(sum2, m);
  if (lane == 0) red[16 + wv] = sum2;
  __syncthreads();
  sum2 = 0.f;
#pragma unroll
  for (int w = 0; w < 8; w++) sum2 += red[16 + w];
  float invs = 1.0f / (sum2 + EPSF);
#pragma unroll
  for (int i = 0; i < 8; i++) {
    int n = tid + i * 512;
    w_out[n] = __float2half(wp[i] * invs);
  }
  __syncthreads();
}

// ---------------- mega: per-b fused passes + chains + reads. grid=256 blocks x 512 thr.
// LDS: w_h fp16 7x4096 (56K) | cb 20x64 f32 (5K) | scr 512x11 f32 (22K) | union tile/wg (64K)
__global__ __launch_bounds__(512, 2) void mega_kernel(
    const float* __restrict__ mem, const float* __restrict__ combo,
    const float* __restrict__ scal, const float* __restrict__ knorm,
    const float* __restrict__ betav, const float* __restrict__ gatev,
    const float* __restrict__ sv, const float* __restrict__ gammav,
    const float* __restrict__ prev_w, unsigned short* __restrict__ mem_bf,
    __half* __restrict__ P, float* __restrict__ reads) {
  extern __shared__ char smem[];
  __half* w_h   = (__half*)smem;                 // 57344 B
  float*  cb    = (float*)(smem + 57344);        // 5120 B
  float*  scr   = (float*)(smem + 62464);        // 22528 B
  char*   un    = smem + 84992;                  // 65536 B
  float4* tile32 = (float4*)un;
  uint4*  tileb  = (uint4*)un;
  float*  wg     = (float*)un;

  int b = blockIdx.x, tid = threadIdx.x;
  size_t bo = (size_t)b * NN;

  for (int i = tid; i < 1280; i += 512) {
    int j = i >> 6, m = i & 63;
    cb[i] = combo[(size_t)j * 16384 + b * 64 + m];
  }
  __syncthreads();

  // ============ phase 1: stream fp32 mem, write bf16 shadow, 9 planes ============
  {
    float kn0 = knorm[0 * BB + b], be0 = betav[0 * BB + b];
    float kn1 = knorm[1 * BB + b], be1 = betav[1 * BB + b];
    float cak2 = scal[b * 8 + 0], cak3 = scal[b * 8 + 1], caa1 = scal[b * 8 + 2];
    const float4* m4 = (const float4*)mem + bo * 16;
    ushort4* mb4 = (ushort4*)mem_bf + bo * 16;
    for (int c = 0; c < 16; c++) {
      int gbase = c * 4096;
#pragma unroll
      for (int i = 0; i < 8; i++) {
        int G = tid + i * 512;
        float4 v = m4[gbase + G];
        int r = G >> 4, q = G & 15;
        tile32[r * 16 + (q ^ (r & 15))] = v;
        ushort4 o;
        o.x = f2bf(v.x); o.y = f2bf(v.y); o.z = f2bf(v.z); o.w = f2bf(v.w);
        mb4[gbase + G] = o;
      }
      __syncthreads();
      int r = tid & 255, qb = (tid >> 8) * 8;
      float a[11];
#pragma unroll
      for (int k = 0; k < 11; k++) a[k] = 0.f;
#pragma unroll
      for (int j = 0; j < 8; j++) {
        int q = qb + j;
        float4 v = tile32[r * 16 + (q ^ (r & 15))];
        float4 sq = make_float4(v.x * v.x, v.y * v.y, v.z * v.z, v.w * v.w);
        a[0] += dot4(v, CL(0, q)); a[1] += dot4(v, CL(1, q));
        a[2] += dot4(v, CL(2, q)); a[3] += dot4(v, CL(3, q));
        a[4] += dot4(v, CL(4, q)); a[5] += dot4(v, CL(5, q));
        a[6] += dot4(v, CL(6, q)); a[7] += dot4(v, CL(7, q));
        a[8] += sq.x + sq.y + sq.z + sq.w;
        a[9] += dot4(sq, CL(8, q)); a[10] += dot4(sq, CL(9, q));
      }
#pragma unroll
      for (int k = 0; k < 11; k++) scr[tid * 11 + k] = a[k];
      __syncthreads();
      if (tid < 256) {
#pragma unroll
        for (int k = 0; k < 11; k++) a[k] = scr[tid * 11 + k] + scr[(tid + 256) * 11 + k];
        int n = c * 256 + tid;
        float rn = sqrtf(a[8]);
        P[0 * PH + bo + n] = __float2half(be0 * a[0] / (rn * kn0 + EPSF));
        P[1 * PH + bo + n] = __float2half(be1 * a[1] / (rn * kn1 + EPSF));
        P[2 * PH + bo + n] = __float2half(a[2]);
        P[3 * PH + bo + n] = __float2half(a[3] - cak2);
        P[4 * PH + bo + n] = __float2half(a[4]);
        P[5 * PH + bo + n] = __float2half(a[5] - cak3);
        P[6 * PH + bo + n] = __float2half(a[8]);
        P[7 * PH + bo + n] = __float2half(a[9] - a[6]);
        P[8 * PH + bo + n] = __float2half(a[10] - 2.f * a[7] + caa1);
      }
      __syncthreads();
    }
  }

  // ============ chains 0..3 ============
  chain_dev(tid, b, 0, P + 0 * PH, nullptr, nullptr, nullptr, nullptr, nullptr,
            w_h, 0, w_h + 0 * NN, wg, scr, knorm, betav, gatev, sv, gammav, prev_w);
  chain_dev(tid, b, 1, P + 1 * PH, nullptr, nullptr, nullptr, nullptr, nullptr,
            w_h, 0, w_h + 1 * NN, wg, scr, knorm, betav, gatev, sv, gammav, prev_w);
  chain_dev(tid, b, 2, nullptr, P + 2 * PH, P + 3 * PH, P + 6 * PH, P + 7 * PH, P + 8 * PH,
            w_h, 1, w_h + 2 * NN, wg, scr, knorm, betav, gatev, sv, gammav, prev_w);
  chain_dev(tid, b, 3, nullptr, P + 4 * PH, P + 5 * PH, P + 6 * PH, P + 7 * PH, P + 8 * PH,
            w_h, 1, w_h + 3 * NN, wg, scr, knorm, betav, gatev, sv, gammav, prev_w);

  // ============ phase 2: stream bf16, build mem2 in regs, 7 planes ============
  {
    float kn4 = knorm[4 * BB + b], be4 = betav[4 * BB + b];
    float kn5 = knorm[5 * BB + b], be5 = betav[5 * BB + b];
    float cak6 = scal[b * 8 + 3], caa5 = scal[b * 8 + 4];
    const uint4* mb16 = (const uint4*)mem_bf + bo * 8;
    for (int c = 0; c < 16; c++) {
      int gbase = c * 2048;
#pragma unroll
      for (int i = 0; i < 4; i++) {
        int G = tid + i * 512;
        uint4 u = mb16[gbase + G];
        int r = G >> 3, g = G & 7;
        tileb[r * 8 + (g ^ (r & 7))] = u;
      }
      __syncthreads();
      int r = tid & 255, gb2 = (tid >> 8) * 4;
      float u1 = __half2float(w_h[1 * NN + c * 256 + r]);
      float u3 = __half2float(w_h[3 * NN + c * 256 + r]);
      float t[9];
#pragma unroll
      for (int k = 0; k < 9; k++) t[k] = 0.f;
#pragma unroll
      for (int j = 0; j < 4; j++) {
        int g = gb2 + j;
        uint4 uv = tileb[r * 8 + (g ^ (r & 7))];
#pragma unroll
        for (int h = 0; h < 2; h++) {
          unsigned int pa = h ? uv.z : uv.x;
          unsigned int pb = h ? uv.w : uv.y;
          float4 v;
          v.x = bf2f(pa & 0xFFFFu); v.y = bf2f(pa >> 16);
          v.z = bf2f(pb & 0xFFFFu); v.w = bf2f(pb >> 16);
          int q = g * 2 + h;
          float4 e1v = CL(8, q), a1v = CL(6, q), e3v = CL(18, q), a3v = CL(19, q);
          float4 m1, m2;
          m1.x = v.x * (1.f - u1 * e1v.x) + u1 * a1v.x;
          m1.y = v.y * (1.f - u1 * e1v.y) + u1 * a1v.y;
          m1.z = v.z * (1.f - u1 * e1v.z) + u1 * a1v.z;
          m1.w = v.w * (1.f - u1 * e1v.w) + u1 * a1v.w;
          m2.x = m1.x * (1.f - u3 * e3v.x) + u3 * a3v.x;
          m2.y = m1.y * (1.f - u3 * e3v.y) + u3 * a3v.y;
          m2.z = m1.z * (1.f - u3 * e3v.z) + u3 * a3v.z;
          m2.w = m1.w * (1.f - u3 * e3v.w) + u3 * a3v.w;
          float4 sq = make_float4(m2.x * m2.x, m2.y * m2.y, m2.z * m2.z, m2.w * m2.w);
          t[0] += dot4(m2, CL(10, q)); t[1] += dot4(m2, CL(11, q));
          t[2] += dot4(m2, CL(12, q)); t[3] += dot4(m2, CL(13, q));
          t[4] += dot4(m2, CL(14, q)); t[5] += dot4(m2, CL(15, q));
          t[6] += sq.x + sq.y + sq.z + sq.w;
          t[7] += dot4(sq, CL(16, q)); t[8] += dot4(sq, CL(17, q));
        }
      }
#pragma unroll
      for (int k = 0; k < 9; k++) scr[tid * 9 + k] = t[k];
      __syncthreads();
      if (tid < 256) {
#pragma unroll
        for (int k = 0; k < 9; k++) t[k] = scr[tid * 9 + k] + scr[(tid + 256) * 9 + k];
        int n = c * 256 + tid;
        float rn = sqrtf(t[6]);
        P[0 * PH + bo + n] = __float2half(be4 * t[0] / (rn * kn4 + EPSF));
        P[1 * PH + bo + n] = __float2half(be5 * t[1] / (rn * kn5 + EPSF));
        P[2 * PH + bo + n] = __float2half(t[2]);
        P[3 * PH + bo + n] = __float2half(t[3] - cak6);
        P[4 * PH + bo + n] = __float2half(t[6]);
        P[5 * PH + bo + n] = __float2half(t[7] - t[4]);
        P[6 * PH + bo + n] = __float2half(t[8] - 2.f * t[5] + caa5);
      }
      __syncthreads();
    }
  }

  // ============ chains 4..6 ============
  chain_dev(tid, b, 4, P + 0 * PH, nullptr, nullptr, nullptr, nullptr, nullptr,
            w_h, 0, w_h + 4 * NN, wg, scr, knorm, betav, gatev, sv, gammav, prev_w);
  chain_dev(tid, b, 5, P + 1 * PH, nullptr, nullptr, nullptr, nullptr, nullptr,
            w_h, 0, w_h + 5 * NN, wg, scr, knorm, betav, gatev, sv, gammav, prev_w);
  chain_dev(tid, b, 6, nullptr, P + 2 * PH, P + 3 * PH, P + 4 * PH, P + 5 * PH, P + 6 * PH,
            w_h, 5, w_h + 6 * NN, wg, scr, knorm, betav, gatev, sv, gammav, prev_w);

  // ============ phase 3: the four reads ============
  {
    int wv = tid >> 6, lane = tid & 63, q = lane & 15, rl = lane >> 4;
    float4 e1v = CL(8, q), a1v = CL(6, q), e3v = CL(18, q), a3v = CL(19, q);
    float4 e5v = CL(16, q), a5v = CL(14, q);
    const ushort4* mbr = (const ushort4*)mem_bf + bo * 16;
    float A[4][4];
#pragma unroll
    for (int j = 0; j < 4; j++)
#pragma unroll
      for (int cmp = 0; cmp < 4; cmp++) A[j][cmp] = 0.f;
#pragma unroll 4
    for (int t = 0; t < 128; t++) {
      int n = t * 32 + wv * 4 + rl;
      ushort4 uv = mbr[(size_t)n * 16 + q];
      float vx = bf2f(uv.x), vy = bf2f(uv.y), vz = bf2f(uv.z), vw = bf2f(uv.w);
      float w0v = __half2float(w_h[0 * NN + n]);
      float u1  = __half2float(w_h[1 * NN + n]);
      float w2v = __half2float(w_h[2 * NN + n]);
      float u3  = __half2float(w_h[3 * NN + n]);
      float w4v = __half2float(w_h[4 * NN + n]);
      float u5  = __half2float(w_h[5 * NN + n]);
      float w6v = __half2float(w_h[6 * NN + n]);
      A[0][0] += w0v * vx; A[0][1] += w0v * vy; A[0][2] += w0v * vz; A[0][3] += w0v * vw;
      float m1x = vx * (1.f - u1 * e1v.x) + u1 * a1v.x;
      float m1y = vy * (1.f - u1 * e1v.y) + u1 * a1v.y;
      float m1z = vz * (1.f - u1 * e1v.z) + u1 * a1v.z;
      float m1w = vw * (1.f - u1 * e1v.w) + u1 * a1v.w;
      A[1][0] += w2v * m1x; A[1][1] += w2v * m1y; A[1][2] += w2v * m1z; A[1][3] += w2v * m1w;
      float m2x = m1x * (1.f - u3 * e3v.x) + u3 * a3v.x;
      float m2y = m1y * (1.f - u3 * e3v.y) + u3 * a3v.y;
      float m2z = m1z * (1.f - u3 * e3v.z) + u3 * a3v.z;
      float m2w = m1w * (1.f - u3 * e3v.w) + u3 * a3v.w;
      A[2][0] += w4v * m2x; A[2][1] += w4v * m2y; A[2][2] += w4v * m2z; A[2][3] += w4v * m2w;
      float m3x = m2x * (1.f - u5 * e5v.x) + u5 * a5v.x;
      float m3y = m2y * (1.f - u5 * e5v.y) + u5 * a5v.y;
      float m3z = m2z * (1.f - u5 * e5v.z) + u5 * a5v.z;
      float m3w = m2w * (1.f - u5 * e5v.w) + u5 * a5v.w;
      A[3][0] += w6v * m3x; A[3][1] += w6v * m3y; A[3][2] += w6v * m3z; A[3][3] += w6v * m3w;
    }
#pragma unroll
    for (int j = 0; j < 4; j++)
#pragma unroll
      for (int cmp = 0; cmp < 4; cmp++) {
        float x = A[j][cmp];
        x += __shfl_xor(x, 16);
        x += __shfl_xor(x, 32);
        A[j][cmp] = x;
      }
    float* sred = scr;  // [4][8][16][4]
    if (rl == 0)
#pragma unroll
      for (int j = 0; j < 4; j++)
#pragma unroll
        for (int cmp = 0; cmp < 4; cmp++)
          sred[((j * 8 + wv) * 16 + q) * 4 + cmp] = A[j][cmp];
    __syncthreads();
    if (tid < 256) {
      int j = tid >> 6, qq = (tid >> 2) & 15, cc = tid & 3;
      float s = 0.f;
#pragma unroll
      for (int w = 0; w < 8; w++) s += sred[((j * 8 + w) * 16 + qq) * 4 + cc];
      reads[(size_t)j * 16384 + b * 64 + qq * 4 + cc] = s;
    }
  }
}

// ---------------- out = sigmoid([h|reads] @ W_out^T + b_out) : [256][64]
__global__ __launch_bounds__(256) void gemm_out_kernel(
    const float* __restrict__ h, const float* __restrict__ reads,
    const float* __restrict__ W_out, const float* __restrict__ b_out,
    float* __restrict__ out) {
  __shared__ float As[16][33];
  __shared__ float Ws[16][65];
  int tid = threadIdx.x, tx = tid & 15, ty = tid >> 4;
  int row0 = blockIdx.y * 32;
  float acc[2][4] = {{0,0,0,0},{0,0,0,0}};
  for (int k0 = 0; k0 < 768; k0 += 16) {
    for (int i = tid; i < 32 * 16; i += 256) {
      int rr = i >> 4, cc = i & 15;
      int row = row0 + rr, k = k0 + cc;
      float v;
      if (k < 512) v = h[row * 512 + k];
      else { int slot = (k - 512) >> 6, m = (k - 512) & 63; v = reads[((size_t)slot * 256 + row) * 64 + m]; }
      As[cc][rr] = v;
    }
    for (int i = tid; i < 64 * 16; i += 256) {
      int rr = i >> 4, cc = i & 15;
      Ws[cc][rr] = W_out[(size_t)rr * 768 + k0 + cc];
    }
    __syncthreads();
#pragma unroll
    for (int kk = 0; kk < 16; kk++) {
      float a0 = As[kk][ty * 2 + 0], a1 = As[kk][ty * 2 + 1];
      float w0 = Ws[kk][tx * 4 + 0], w1 = Ws[kk][tx * 4 + 1];
      float w2 = Ws[kk][tx * 4 + 2], w3 = Ws[kk][tx * 4 + 3];
      acc[0][0] += a0 * w0; acc[0][1] += a0 * w1; acc[0][2] += a0 * w2; acc[0][3] += a0 * w3;
      acc[1][0] += a1 * w0; acc[1][1] += a1 * w1; acc[1][2] += a1 * w2; acc[1][3] += a1 * w3;
    }
    __syncthreads();
  }
  for (int i = 0; i < 2; i++)
    for (int j = 0; j < 4; j++) {
      int cc = tx * 4 + j;
      out[(size_t)(row0 + ty * 2 + i) * 64 + cc] = sigf(acc[i][j] + b_out[cc]);
    }
}

extern "C" void kernel_launch(void* const* d_in, const int* in_sizes, int n_in,
                              void* d_out, int out_size, void* d_ws, size_t ws_size,
                              hipStream_t stream) {
  const float* in_data = (const float*)d_in[0];
  const float* memory  = (const float*)d_in[1];
  const float* h0      = (const float*)d_in[2];
  const float* c0      = (const float*)d_in[3];
  const float* prev_w  = (const float*)d_in[4];
  const float* prev_r  = (const float*)d_in[5];
  const float* W_ih    = (const float*)d_in[6];
  const float* b_ih    = (const float*)d_in[7];
  const float* W_hh    = (const float*)d_in[8];
  const float* b_hh    = (const float*)d_in[9];
  const float* W_out   = (const float*)d_in[10];
  const float* b_out   = (const float*)d_in[11];
  const float* W_addr  = (const float*)d_in[12];
  const float* b_addr  = (const float*)d_in[13];
  const float* W_ea    = (const float*)d_in[14];
  const float* b_ea    = (const float*)d_in[15];
  float* out = (float*)d_out;
  (void)in_sizes; (void)n_in; (void)out_size; (void)ws_size;

  float* ws = (float*)d_ws;
  size_t off = 0;
  auto alloc = [&](size_t n) { float* p = ws + off; off += (n + 63) & ~(size_t)63; return p; };
  float* gates  = alloc(256 * 2048);
  float* cbuf   = alloc(256 * 512);
  float* hbuf   = alloc(256 * 512);
  float* p_raw  = alloc(256 * 1072);
  float* knorm  = alloc(8 * 256);
  float* betav  = alloc(8 * 256);
  float* gatev  = alloc(8 * 256);
  float* sv     = alloc(8 * 256 * 3);
  float* gammav = alloc(8 * 256);
  float* combo  = alloc(20 * 16384);
  float* scal   = alloc(256 * 8);
  __half* P     = (__half*)alloc(9 * PH / 2);           // 9 fp16 planes
  float* reads  = alloc(4 * 16384);
  unsigned short* mem_bf = (unsigned short*)alloc(33554432); // 128 MB bf16 copy

  static bool attr_set = false;
  if (!attr_set) {
    hipFuncSetAttribute((const void*)mega_kernel,
                        hipFuncAttributeMaxDynamicSharedMemorySize, 150528);
    attr_set = true;
  }

  gemm_gates_kernel<<<dim3(32, 8), 256, 0, stream>>>(in_data, prev_r, h0, W_ih, W_hh, b_ih, b_hh, gates);
  lstm_elem_kernel<<<(256 * 512 + 255) / 256, 256, 0, stream>>>(gates, c0, cbuf, hbuf);
  gemm_heads_kernel<<<dim3(17, 8), 256, 0, stream>>>(cbuf, W_addr, W_ea, b_addr, b_ea, p_raw);
  params_kernel<<<256, 64, 0, stream>>>(p_raw, knorm, betav, gatev, sv, gammav, combo, scal);
  mega_kernel<<<256, 512, 150528, stream>>>(memory, combo, scal, knorm, betav, gatev,
                                            sv, gammav, prev_w, mem_bf, P, reads);
  gemm_out_kernel<<<dim3(1, 8), 256, 0, stream>>>(hbuf, reads, W_out, b_out, out);
}